// Round 14
// baseline (146.229 us; speedup 1.0000x reference)
//
#include <hip/hip_runtime.h>
#include <hip/hip_fp16.h>

#define EPS 1e-5f

typedef float f32x4 __attribute__((ext_vector_type(4)));
typedef short bf16x8 __attribute__((ext_vector_type(8)));
typedef short bf16x4 __attribute__((ext_vector_type(4)));

__device__ __forceinline__ unsigned short f2b(float f){
  unsigned u=__float_as_uint(f);
  return (unsigned short)((u + 0x7fffu + ((u>>16)&1u))>>16);
}
__device__ __forceinline__ float b2f(unsigned short h){
  return __uint_as_float(((unsigned)h)<<16);
}

// ---------------- helpers ----------------
__device__ __forceinline__ float blockSum256(float v, float* red){
  #pragma unroll
  for(int o=32;o>0;o>>=1) v += __shfl_down(v,o,64);
  int wid = threadIdx.x>>6;
  if((threadIdx.x&63)==0) red[wid]=v;
  __syncthreads();
  if(threadIdx.x==0) red[0]=red[0]+red[1]+red[2]+red[3];
  __syncthreads();
  float r = red[0];
  __syncthreads();
  return r;
}

// ---------------- KBP: fused prep — mcT transpose (blocks 0..767) + weight packing (768..1068) ----
__global__ __launch_bounds__(256) void kbp_prep(const float* __restrict__ adj, const float* __restrict__ cmask,
    const float* __restrict__ cheb, unsigned* __restrict__ mcT,
    const float* __restrict__ g3w, const float* __restrict__ g5w,
    const float* __restrict__ g7w, const float* __restrict__ swq, const float* __restrict__ swk,
    const float* __restrict__ wq, const float* __restrict__ wk, const float* __restrict__ wv,
    const float* __restrict__ fcw, const float* __restrict__ fcW,
    unsigned short* __restrict__ Apack, unsigned short* __restrict__ Wpack,
    unsigned short* __restrict__ Wpack2, unsigned short* __restrict__ fcwB,
    unsigned short* __restrict__ fcWB2){
  int tid=threadIdx.x;
  if(blockIdx.x<768){
    int blk=blockIdx.x;                 // k*256 + tn*16 + tm
    int k=blk>>8; int rem=blk&255; int tn=rem>>4, tm=rem&15;
    __shared__ unsigned tile[64][65];
    const float* chk = cheb + k*1048576;
    const float* cmk = cmask + k*1048576;
    for(int i=tid;i<4096;i+=256){
      int ln=i>>6, lm=i&63;
      int n=tn*64+ln, m=tm*64+lm;
      int nm=n*1024+m;
      tile[ln][lm] = (((unsigned)f2b(chk[nm]))<<16) | (unsigned)f2b(adj[nm]*cmk[nm]);
    }
    __syncthreads();
    unsigned* dst = mcT + k*1048576;
    for(int i=tid;i<4096;i+=256){
      int lm=i>>6, ln=i&63;
      dst[(tm*64+lm)*1024 + tn*64+ln] = tile[ln][lm];
    }
    return;
  }
  int idx = (blockIdx.x-768)*256+tid;
  if(idx<15360){                                   // Apack (conv A-frags, bf16)
    int frag=idx>>6, lane=idx&63;
    int rt, s, kappa; const float* W;
    if(frag<48){ rt=frag/6; s=frag-rt*6; kappa=3; W=g3w; }
    else if(frag<128){ int f=frag-48; rt=f/10; s=f-rt*10; kappa=5; W=g5w; }
    else { int f=frag-128; rt=f/14; s=f-rt*14; kappa=7; W=g7w; }
    int c = rt*16 + (lane&15);
    int dt = s>>1, ic0=(s&1)*32 + (lane>>4)*8;
    #pragma unroll
    for(int j=0;j<8;j++) Apack[idx*8+j]=f2b(W[(c*64+ic0+j)*kappa + dt]);
  } else if(idx<27648){                            // Wpack (swq/swk B-frags)
    int id2=idx-15360;
    int frag=id2>>6, lane=id2&63;
    int ct=frag>>4, ks=frag&15;
    const float* W = (ct<6)? swq : swk;
    int c = ((ct<6)? ct : ct-6)*16 + (lane&15);
    int k0 = ks*32 + (lane>>4)*8;
    #pragma unroll
    for(int j=0;j<8;j++) Wpack[id2*8+j]=f2b(W[(k0+j)*96 + c]);
  } else if(idx<64512){                            // Wpack2 (wq|wk|wv B-frags)
    int id2=idx-27648;
    int frag=id2>>6, lane=id2&63;
    int ct=frag>>5, ks=frag&31;
    int cg = ct*16 + (lane&15);
    const float* W; int c;
    if(cg<96){ W=wq; c=cg; } else if(cg<192){ W=wk; c=cg-96; } else { W=wv; c=cg-192; }
    int k0 = ks*32 + (lane>>4)*8;
    #pragma unroll
    for(int j=0;j<8;j++) Wpack2[id2*8+j]=f2b(W[(k0+j)*96 + c]);
  } else if(idx<64576){                            // fcwB (bf16)
    int lane=idx-64512;
    int t=lane&15, hq=lane>>4;
    #pragma unroll
    for(int j=0;j<8;j++){
      int tau=hq*8+j;
      fcwB[lane*8+j] = (tau<24 && t<12) ? f2b(fcw[tau*12+t]) : (unsigned short)0;
    }
  } else if(idx<76864){                            // fcWB2 (fcW B-frags: 64 ct x 3 ks)
    int id3=idx-64576;
    int frag=id3>>6, lane=id3&63;
    int ct=frag/3, ks=frag-ct*3;
    int c = ct*16 + (lane&15);
    int k0 = ks*32 + (lane>>4)*8;
    #pragma unroll
    for(int j=0;j<8;j++) fcWB2[id3*8+j]=f2b(fcW[(k0+j)*1024 + c]);
  }
}

// ---------------- K1: EmbedT (fp32 + bf16 outputs) ----------------
__global__ __launch_bounds__(256) void k1_embedT(const float* __restrict__ x, const float* __restrict__ posT,
    const float* __restrict__ gT, const float* __restrict__ bT, float* __restrict__ TEmx,
    unsigned short* __restrict__ TEb){
  int bt=blockIdx.x; int b=bt/12, t=bt-b*12;
  int tid=threadIdx.x;
  __shared__ float red[4];
  float v[4]; float s=0.f;
  #pragma unroll
  for(int i=0;i<4;i++){ int n=tid+i*256; v[i]=x[(b*1024+n)*12+t]+posT[t*1024+n]; s+=v[i]; }
  s = blockSum256(s, red);
  float mu = s*(1.f/1024.f);
  float q=0.f;
  #pragma unroll
  for(int i=0;i<4;i++){ float d=v[i]-mu; q+=d*d; }
  q = blockSum256(q, red);
  float rstd = rsqrtf(q*(1.f/1024.f)+EPS);
  #pragma unroll
  for(int i=0;i<4;i++){
    int n=tid+i*256;
    float val=(v[i]-mu)*rstd*gT[n]+bT[n];
    TEmx[bt*1024+n]=val;
    TEb[bt*1024+n]=f2b(val);
  }
}

// ---------------- K2: QKV via MFMA split-K GEMM ----------------
__global__ __launch_bounds__(256) void k2_qkv(const unsigned short* __restrict__ TEb,
    const unsigned short* __restrict__ Wpack2, float* __restrict__ qkv){
  int tid=threadIdx.x; int w=tid>>6, lane=tid&63;
  const int hi=lane>>4, lo=lane&15;
  const int rt=blockIdx.x/18, ct=blockIdx.x-rt*18;
  __shared__ float red[4][16][16];
  f32x4 acc={0.f,0.f,0.f,0.f};
  #pragma unroll
  for(int s=0;s<8;s++){
    int ks=w*8+s;
    bf16x8 af = *(const bf16x8*)&TEb[(rt*16+lo)*1024 + ks*32 + hi*8];
    bf16x8 bf = *(const bf16x8*)&Wpack2[((ct*32+ks)<<9) + lane*8];
    acc = __builtin_amdgcn_mfma_f32_16x16x32_bf16(af, bf, acc, 0,0,0);
  }
  #pragma unroll
  for(int r=0;r<4;r++) red[w][hi*4+r][lo]=acc[r];
  __syncthreads();
  int r16=tid>>4, c16=tid&15;
  float s = red[0][r16][c16]+red[1][r16][c16]+red[2][r16][c16]+red[3][r16][c16];
  qkv[(rt*16+r16)*288 + ct*16 + c16] = s;
}

// ---------------- K3: temporal attn, 48 blocks (b,h) ----------------
__global__ __launch_bounds__(256) void k3_attn(const float* __restrict__ qkv, const float* __restrict__ res_att,
    float* __restrict__ scores_out, unsigned short* __restrict__ ctxb){
  int bh=blockIdx.x; int b=bh/3, h=bh-(bh/3)*3;
  int tid=threadIdx.x;
  __shared__ float sS[144];
  __shared__ float sA[144];
  if(tid<144){
    int q=tid/12;
    const float* Qr=&qkv[(b*12+q)*288 + h*32];
    const float* Kr=&qkv[(b*12+(tid-q*12))*288 + 96 + h*32];
    float acc=0.f;
    #pragma unroll
    for(int d=0;d<32;d++) acc+=Qr[d]*Kr[d];
    acc = acc*0.17677669529663687f + res_att[bh*144 + tid];
    sS[tid]=acc;
    scores_out[bh*144 + tid]=acc;
  }
  __syncthreads();
  if(tid<12){
    int k2=tid;
    float mx=-1e30f;
    for(int q=0;q<12;q++) mx=fmaxf(mx,sS[q*12+k2]);
    float sum=0.f;
    for(int q=0;q<12;q++){ float e=__expf(sS[q*12+k2]-mx); sA[q*12+k2]=e; sum+=e; }
    float inv=1.f/sum;
    for(int q=0;q<12;q++) sA[q*12+k2]*=inv;
  }
  __syncthreads();
  for(int o=tid;o<384;o+=256){
    int q=o>>5, d=o&31;
    float acc=0.f;
    #pragma unroll
    for(int k2=0;k2<12;k2++) acc += sA[q*12+k2]*qkv[(b*12+k2)*288+192+h*32+d];
    ctxb[(b*12+q)*96 + h*32 + d]=f2b(acc);
  }
}

// ---------------- K4a: TATpre = ctx@fcW + TEmx via MFMA ----------------
__global__ __launch_bounds__(256) void k4a_mm(const unsigned short* __restrict__ ctxb,
    const unsigned short* __restrict__ fcWB2, const float* __restrict__ TEmx,
    float* __restrict__ TATpre){
  int tid=threadIdx.x; int w=tid>>6, lane=tid&63;
  const int hi=lane>>4, lo=lane&15;
  const int rt=blockIdx.x>>4, cg=blockIdx.x&15;
  const int ct=cg*4+w;
  f32x4 acc={0.f,0.f,0.f,0.f};
  #pragma unroll
  for(int ks=0;ks<3;ks++){
    bf16x8 af = *(const bf16x8*)&ctxb[(rt*16+lo)*96 + ks*32 + hi*8];
    bf16x8 bf = *(const bf16x8*)&fcWB2[((ct*3+ks)<<9) + lane*8];
    acc = __builtin_amdgcn_mfma_f32_16x16x32_bf16(af, bf, acc, 0,0,0);
  }
  #pragma unroll
  for(int r=0;r<4;r++){
    int row = rt*16 + hi*4 + r;
    int coln = ct*16 + lo;
    TATpre[row*1024+coln] = acc[r] + TEmx[row*1024+coln];
  }
}

// ---------------- K4b: per-row LN stats ----------------
__global__ __launch_bounds__(256) void k4b_stats(const float* __restrict__ TATpre,
    float* __restrict__ muT, float* __restrict__ rsT){
  int bt=blockIdx.x; int tid=threadIdx.x;
  __shared__ float red[4];
  const float* row=&TATpre[bt*1024];
  float a0=row[tid], a1=row[tid+256], a2=row[tid+512], a3=row[tid+768];
  float s=a0+a1+a2+a3;
  s=blockSum256(s,red);
  float mu=s*(1.f/1024.f);
  float q=(a0-mu)*(a0-mu)+(a1-mu)*(a1-mu)+(a2-mu)*(a2-mu)+(a3-mu)*(a3-mu);
  q=blockSum256(q,red);
  if(tid==0){ muT[bt]=mu; rsT[bt]=rsqrtf(q*(1.f/1024.f)+EPS); }
}

// ---------------- K5: SEmx, 8 rows/block; LN applied on tv load ----------------
__global__ __launch_bounds__(256) void k5_semx(const float* __restrict__ TATpre,
    const float* __restrict__ muT, const float* __restrict__ rsT,
    const float* __restrict__ pre_w,
    const float* __restrict__ pre_b, const float* __restrict__ posS, const float* __restrict__ gS,
    const float* __restrict__ bS, unsigned short* __restrict__ SEb){
  int bn0=blockIdx.x*8; int b=bn0>>10, n0=bn0&1023; int tid=threadIdx.x;
  __shared__ float tv[12][8];
  __shared__ float ps[8][264];
  __shared__ float pq[8][264];
  __shared__ float mur[8], rsr[8];
  if(tid<96){
    int r=tid&7, t=tid>>3;
    int bt=b*12+t;
    tv[t][r]=(TATpre[bt*1024+n0+r]-muT[bt])*rsT[bt];
  }
  __syncthreads();
  const int d0=tid, d1=tid+256;
  float w0[12], w1[12];
  {
    const float4* p0=(const float4*)&pre_w[d0*12];
    float4 a=p0[0], bb=p0[1], c=p0[2];
    w0[0]=a.x;w0[1]=a.y;w0[2]=a.z;w0[3]=a.w; w0[4]=bb.x;w0[5]=bb.y;w0[6]=bb.z;w0[7]=bb.w;
    w0[8]=c.x;w0[9]=c.y;w0[10]=c.z;w0[11]=c.w;
    const float4* p1=(const float4*)&pre_w[d1*12];
    float4 d=p1[0], e=p1[1], f=p1[2];
    w1[0]=d.x;w1[1]=d.y;w1[2]=d.z;w1[3]=d.w; w1[4]=e.x;w1[5]=e.y;w1[6]=e.z;w1[7]=e.w;
    w1[8]=f.x;w1[9]=f.y;w1[10]=f.z;w1[11]=f.w;
  }
  float pb0=pre_b[d0], pb1=pre_b[d1];
  float v0[8], v1[8];
  #pragma unroll
  for(int r=0;r<8;r++){
    float acc0=pb0 + posS[(n0+r)*512+d0];
    float acc1=pb1 + posS[(n0+r)*512+d1];
    #pragma unroll
    for(int t=0;t<12;t++){ float tvv=tv[t][r]; acc0+=tvv*w0[t]; acc1+=tvv*w1[t]; }
    v0[r]=acc0; v1[r]=acc1;
    ps[r][tid]=acc0+acc1;
    pq[r][tid]=acc0*acc0+acc1*acc1;
  }
  __syncthreads();
  {
    int row=tid>>5, l32=tid&31;
    float s=0.f, q=0.f;
    #pragma unroll
    for(int j=0;j<8;j++){ s+=ps[row][l32+j*32]; q+=pq[row][l32+j*32]; }
    #pragma unroll
    for(int o=16;o>=1;o>>=1){ s+=__shfl_xor(s,o,64); q+=__shfl_xor(q,o,64); }
    if(l32==0){
      float mu=s*(1.f/512.f);
      float var=q*(1.f/512.f)-mu*mu;
      mur[row]=mu; rsr[row]=rsqrtf(var+EPS);
    }
  }
  __syncthreads();
  float g0=gS[d0], b0v=bS[d0], g1=gS[d1], b1v=bS[d1];
  #pragma unroll
  for(int r=0;r<8;r++){
    float mu=mur[r], rs=rsr[r];
    SEb[(bn0+r)*512 + d0] = f2b((v0[r]-mu)*rs*g0+b0v);
    SEb[(bn0+r)*512 + d1] = f2b((v1[r]-mu)*rs*g1+b1v);
  }
}

// ---------------- K6: SQ/SK via MFMA GEMM, 16 rows/block; af prefetch ----------------
__global__ __launch_bounds__(256) void k6_sqk(const unsigned short* __restrict__ SEb,
    const unsigned short* __restrict__ Wpack,
    unsigned short* __restrict__ SQb, unsigned short* __restrict__ SKb){
  int tid=threadIdx.x; int w=tid>>6, lane=tid&63;
  const int hi=lane>>4, lo=lane&15;
  const int row0 = blockIdx.x*16;
  f32x4 acc[3];
  #pragma unroll
  for(int i=0;i<3;i++){ acc[i][0]=0.f; acc[i][1]=0.f; acc[i][2]=0.f; acc[i][3]=0.f; }
  const unsigned short* arow = &SEb[(row0+lo)*512 + hi*8];
  bf16x8 afc = *(const bf16x8*)&arow[0];
  #pragma unroll
  for(int ks=0;ks<16;ks++){
    bf16x8 afn;
    if(ks<15) afn = *(const bf16x8*)&arow[(ks+1)*32];
    #pragma unroll
    for(int j=0;j<3;j++){
      int ct = w*3+j;
      bf16x8 bf = *(const bf16x8*)&Wpack[((ct*16+ks)<<9) + lane*8];
      acc[j] = __builtin_amdgcn_mfma_f32_16x16x32_bf16(afc, bf, acc[j], 0,0,0);
    }
    if(ks<15) afc = afn;
  }
  #pragma unroll
  for(int j=0;j<3;j++){
    int ct = w*3+j;
    int c96 = ((ct<6)? ct : ct-6)*16 + lo;
    int kq = c96>>5, d = c96&31;
    unsigned short* dst = (ct<6)? SQb : SKb;
    #pragma unroll
    for(int r=0;r<4;r++){
      int n = row0 + hi*4 + r;
      int b = n>>10, nl = n&1023;
      dst[((b*3+kq)*1024+nl)*32 + d] = f2b(acc[j][r]);
    }
  }
}

// ---------------- K7: whole-x LDS stage; prefetch; setprio around MFMA ----------------
#define SCALE7 0.17677669529663687f
__global__ __launch_bounds__(256) void k7_spatial(const unsigned short* __restrict__ SQb,
    const unsigned short* __restrict__ SKb, const unsigned* __restrict__ mcT,
    const float* __restrict__ x, float* __restrict__ rhsT){
  const int blk0=blockIdx.x;
  const int blk=(blk0&7)*96 + (blk0>>3);      // XCD-chunked: 768 = 8*96, bijective
  const int mt=blk&15, bk=blk>>4;
  const int k=bk%3, b=bk/3;
  const int m0=mt*64;
  const int tid=threadIdx.x;
  const int w=tid>>6, lane=tid&63, g=lane>>4, col=lane&15;

  __shared__ unsigned short xs[16*1024];

  const float* xb = x + b*12288;
  for(int i=tid;i<2048;i+=256) ((unsigned*)xs)[12*512 + i] = 0u;
  for(int i=tid;i<12288;i+=256){
    int n=i/12, t=i-n*12;
    xs[t*1024 + (n ^ ((t&7)<<3))] = f2b(xb[i]);
  }
  __syncthreads();

  const int m_glob = m0 + w*16 + col;
  bf16x8 bfrag = *(const bf16x8*)&SKb[((bk<<10)+m_glob)*32 + g*8];

  f32x4 O = {0.f,0.f,0.f,0.f};
  float mrun=-1e30f, lrun=0.f;

  const unsigned* mrow = mcT + k*1048576 + m_glob*1024;
  const unsigned short* sqbase = &SQb[((bk<<10)+col)*32 + g*8];
  const int swz = (col&7)<<3;

  uint4 mvc[8]; bf16x8 afc[8];
  #pragma unroll
  for(int nt=0;nt<8;nt++){
    mvc[nt] = *(const uint4*)&mrow[nt*16 + g*4];
    afc[nt] = *(const bf16x8*)&sqbase[(nt*16)*32];
  }

  #pragma unroll
  for(int ch=0; ch<8; ++ch){
    const int n0 = ch<<7;
    uint4 mvn[8]; bf16x8 afn[8];
    #pragma unroll
    for(int nt=0;nt<8;nt++){
      if(ch<7){
        mvn[nt] = *(const uint4*)&mrow[n0+128 + nt*16 + g*4];
        afn[nt] = *(const bf16x8*)&sqbase[(n0+128 + nt*16)*32];
      }
    }

    f32x4 acc[8];
    __builtin_amdgcn_s_setprio(1);
    #pragma unroll
    for(int nt=0;nt<8;nt++){
      f32x4 z = {0.f,0.f,0.f,0.f};
      acc[nt] = __builtin_amdgcn_mfma_f32_16x16x32_bf16(afc[nt], bfrag, z, 0,0,0);
    }
    __builtin_amdgcn_s_setprio(0);
    float cmax = -1e30f;
    #pragma unroll
    for(int nt=0;nt<8;nt++){
      #pragma unroll
      for(int r=0;r<4;r++){
        unsigned mv = (r==0)?mvc[nt].x:((r==1)?mvc[nt].y:((r==2)?mvc[nt].z:mvc[nt].w));
        float s = acc[nt][r]*SCALE7 + __uint_as_float(mv<<16);
        acc[nt][r]=s;
        cmax=fmaxf(cmax,s);
      }
    }
    cmax = fmaxf(cmax, __shfl_xor(cmax,16,64));
    cmax = fmaxf(cmax, __shfl_xor(cmax,32,64));
    float mnew = fmaxf(mrun, cmax);
    float alpha = __expf(mrun - mnew);
    float lsum = 0.f;
    unsigned short pb[8][4];
    #pragma unroll
    for(int nt=0;nt<8;nt++){
      #pragma unroll
      for(int r=0;r<4;r++){
        unsigned mv = (r==0)?mvc[nt].x:((r==1)?mvc[nt].y:((r==2)?mvc[nt].z:mvc[nt].w));
        float e = __expf(acc[nt][r] - mnew);
        lsum += e;
        pb[nt][r] = f2b(e * __uint_as_float(mv & 0xffff0000u));
      }
    }
    lsum += __shfl_xor(lsum,16,64);
    lsum += __shfl_xor(lsum,32,64);
    lrun = lrun*alpha + lsum;
    mrun = mnew;
    O[0]*=alpha; O[1]*=alpha; O[2]*=alpha; O[3]*=alpha;

    __builtin_amdgcn_s_setprio(1);
    #pragma unroll
    for(int c=0;c<4;c++){
      bf16x8 pf;
      #pragma unroll
      for(int j=0;j<4;j++){ pf[j]=(short)pb[2*c][j]; pf[j+4]=(short)pb[2*c+1][j]; }
      int nlo = n0 + c*32 + g*4;
      bf16x4 lo = *(const bf16x4*)&xs[col*1024 + (nlo ^ swz)];
      bf16x4 hi = *(const bf16x4*)&xs[col*1024 + ((nlo+16) ^ swz)];
      bf16x8 ax;
      #pragma unroll
      for(int j=0;j<4;j++){ ax[j]=lo[j]; ax[j+4]=hi[j]; }
      O = __builtin_amdgcn_mfma_f32_16x16x32_bf16(ax, pf, O, 0,0,0);
    }
    __builtin_amdgcn_s_setprio(0);
    #pragma unroll
    for(int nt=0;nt<8;nt++){
      if(ch<7){ mvc[nt]=mvn[nt]; afc[nt]=afn[nt]; }
    }
  }
  float inv = 1.f/lrun;
  #pragma unroll
  for(int r=0;r<4;r++){
    int t = g*4+r;
    if(t<12) rhsT[((bk*12+t)<<10) + m_glob] = O[r]*inv;
  }
}

// ---------------- K9: conv MFMA (setprio) -> gated LDS -> fc MFMA -> residual+LN ----
__global__ __launch_bounds__(256) void k9_final(const float* __restrict__ rhsT, const float* __restrict__ theta,
    const unsigned short* __restrict__ Apack, const unsigned short* __restrict__ fcwB,
    const float* __restrict__ g3b, const float* __restrict__ g5b, const float* __restrict__ g7b,
    const float* __restrict__ fcb,
    const float* __restrict__ rw, const float* __restrict__ rb,
    const float* __restrict__ gln, const float* __restrict__ bln,
    const float* __restrict__ x, float* __restrict__ out){
  int bn0=blockIdx.x*8;
  int tid=threadIdx.x;
  const int b=bn0>>10, n0=bn0&1023;

  __shared__ struct { unsigned short Xl[12*8*64]; float rstage[3][12][8]; } P0;
  __shared__ union {
    unsigned short Gl[4*16*8*24];   // [wave][c_loc][g'][tau]
    float XP[8][772];
  } U;
  __shared__ float xres[8][12];
  __shared__ float mu8[8][12], rs8[8][12];

  for(int i=tid;i<288;i+=256){
    int kk=i/96; int rem=i-kk*96; int t=rem>>3; int g=rem&7;
    P0.rstage[kk][t][g]=rhsT[((b*3+kk)*12+t)*1024 + n0 + g];
  }
  for(int i=tid;i<96;i+=256){ int g=i/12, t=i-(i/12)*12; xres[g][t]=x[(bn0+g)*12+t]; }
  __syncthreads();

  {
    int g=tid>>5, icp=tid&31;
    float th0[3], th1[3];
    #pragma unroll
    for(int kk=0;kk<3;kk++){ th0[kk]=theta[kk*64+2*icp]; th1[kk]=theta[kk*64+2*icp+1]; }
    #pragma unroll
    for(int t=0;t<12;t++){
      float r0=P0.rstage[0][t][g], r1=P0.rstage[1][t][g], r2=P0.rstage[2][t][g];
      float a0=fmaxf(r0*th0[0]+r1*th0[1]+r2*th0[2],0.f);
      float a1=fmaxf(r0*th1[0]+r1*th1[1]+r2*th1[2],0.f);
      unsigned pack = (((unsigned)f2b(a1))<<16)|(unsigned)f2b(a0);
      *(unsigned*)((char*)P0.Xl + ((t*8+g)<<7) + ((icp*4) ^ (g<<4))) = pack;
    }
  }
  __syncthreads();

  const int w=tid>>6, lane=tid&63, halfk=lane>>4, colq=lane&15;
  const int gg=colq&7, tau2=colq>>3;
  const int ca = w*16 + halfk*4;
  const char* xlb = (const char*)P0.Xl;
  unsigned short* Glw = &U.Gl[w*3072];

  #define GATE_STORE(ACCA, ACCB, TB) { \
    _Pragma("unroll") \
    for(int r=0;r<4;r++){ \
      float ya=(ACCA)[r], yb=(ACCB)[r]; \
      float e2=__expf(2.f*ya), eb=__expf(yb); \
      float gval=(e2-1.f)*eb*__frcp_rn((e2+1.f)*(eb+1.f)); \
      int c_loc=halfk*4+r; \
      Glw[c_loc*192 + ((gg ^ (c_loc&7))*24) + (TB)+tau2] = f2b(gval); \
    } }

  // ---- group kappa=3 (6 K-steps, 5 col-tiles) ----
  {
    f32x4 acA[5], acB[5];
    #pragma unroll
    for(int j=0;j<5;j++)
      #pragma unroll
      for(int r=0;r<4;r++){ acA[j][r]=g3b[ca+r]; acB[j][r]=g3b[64+ca+r]; }
    const unsigned short* ap0=&Apack[((w  )*6)*512 + lane*8];
    const unsigned short* ap1=&Apack[((w+4)*6)*512 + lane*8];
    bf16x8 a0c=*(const bf16x8*)&ap0[0];
    bf16x8 a1c=*(const bf16x8*)&ap1[0];
    #pragma unroll
    for(int s=0;s<6;s++){
      bf16x8 a0n, a1n;
      if(s<5){ a0n=*(const bf16x8*)&ap0[(s+1)*512]; a1n=*(const bf16x8*)&ap1[(s+1)*512]; }
      int dt=s>>1;
      int sl = ((((s&1)*32 + halfk*8)*2) ^ (gg<<4));
      __builtin_amdgcn_s_setprio(1);
      #pragma unroll
      for(int j=0;j<5;j++){
        int t=2*j+tau2+dt;
        bf16x8 bf = *(const bf16x8*)(xlb + ((t*8+gg)<<7) + sl);
        acA[j] = __builtin_amdgcn_mfma_f32_16x16x32_bf16(a0c, bf, acA[j], 0,0,0);
        acB[j] = __builtin_amdgcn_mfma_f32_16x16x32_bf16(a1c, bf, acB[j], 0,0,0);
      }
      __builtin_amdgcn_s_setprio(0);
      if(s<5){ a0c=a0n; a1c=a1n; }
    }
    #pragma unroll
    for(int j=0;j<5;j++) GATE_STORE(acA[j], acB[j], 2*j)
  }
  // ---- group kappa=5 (10 K-steps, 4 col-tiles) ----
  {
    f32x4 acA[4], acB[4];
    #pragma unroll
    for(int j=0;j<4;j++)
      #pragma unroll
      for(int r=0;r<4;r++){ acA[j][r]=g5b[ca+r]; acB[j][r]=g5b[64+ca+r]; }
    const unsigned short* ap0=&Apack[(48 + (w  )*10)*512 + lane*8];
    const unsigned short* ap1=&Apack[(48 + (w+4)*10)*512 + lane*8];
    bf16x8 a0c=*(const bf16x8*)&ap0[0];
    bf16x8 a1c=*(const bf16x8*)&ap1[0];
    #pragma unroll
    for(int s=0;s<10;s++){
      bf16x8 a0n, a1n;
      if(s<9){ a0n=*(const bf16x8*)&ap0[(s+1)*512]; a1n=*(const bf16x8*)&ap1[(s+1)*512]; }
      int dt=s>>1;
      int sl = ((((s&1)*32 + halfk*8)*2) ^ (gg<<4));
      __builtin_amdgcn_s_setprio(1);
      #pragma unroll
      for(int j=0;j<4;j++){
        int t=2*j+tau2+dt;
        bf16x8 bf = *(const bf16x8*)(xlb + ((t*8+gg)<<7) + sl);
        acA[j] = __builtin_amdgcn_mfma_f32_16x16x32_bf16(a0c, bf, acA[j], 0,0,0);
        acB[j] = __builtin_amdgcn_mfma_f32_16x16x32_bf16(a1c, bf, acB[j], 0,0,0);
      }
      __builtin_amdgcn_s_setprio(0);
      if(s<9){ a0c=a0n; a1c=a1n; }
    }
    #pragma unroll
    for(int j=0;j<4;j++) GATE_STORE(acA[j], acB[j], 10+2*j)
  }
  // ---- group kappa=7 (14 K-steps, 3 col-tiles) ----
  {
    f32x4 acA[3], acB[3];
    #pragma unroll
    for(int j=0;j<3;j++)
      #pragma unroll
      for(int r=0;r<4;r++){ acA[j][r]=g7b[ca+r]; acB[j][r]=g7b[64+ca+r]; }
    const unsigned short* ap0=&Apack[(128 + (w  )*14)*512 + lane*8];
    const unsigned short* ap1=&Apack[(128 + (w+4)*14)*512 + lane*8];
    bf16x8 a0c=*(const bf16x8*)&ap0[0];
    bf16x8 a1c=*(const bf16x8*)&ap1[0];
    #pragma unroll
    for(int s=0;s<14;s++){
      bf16x8 a0n, a1n;
      if(s<13){ a0n=*(const bf16x8*)&ap0[(s+1)*512]; a1n=*(const bf16x8*)&ap1[(s+1)*512]; }
      int dt=s>>1;
      int sl = ((((s&1)*32 + halfk*8)*2) ^ (gg<<4));
      __builtin_amdgcn_s_setprio(1);
      #pragma unroll
      for(int j=0;j<3;j++){
        int t=2*j+tau2+dt;
        bf16x8 bf = *(const bf16x8*)(xlb + ((t*8+gg)<<7) + sl);
        acA[j] = __builtin_amdgcn_mfma_f32_16x16x32_bf16(a0c, bf, acA[j], 0,0,0);
        acB[j] = __builtin_amdgcn_mfma_f32_16x16x32_bf16(a1c, bf, acB[j], 0,0,0);
      }
      __builtin_amdgcn_s_setprio(0);
      if(s<13){ a0c=a0n; a1c=a1n; }
    }
    #pragma unroll
    for(int j=0;j<3;j++) GATE_STORE(acA[j], acB[j], 18+2*j)
  }
  #undef GATE_STORE

  // ---- fc via MFMA ----
  const int tcol = lane&15, hq = lane>>4;
  const int hm = (hq==3)? 0 : hq;
  bf16x8 b2 = *(const bf16x8*)&fcwB[lane*8];
  float fcbv = (tcol<12)? fcb[tcol] : 0.f;
  f32x4 d2[8];
  #pragma unroll
  for(int g=0; g<8; g++){
    bf16x8 a2 = *(const bf16x8*)&Glw[tcol*192 + ((g ^ (tcol&7))*24) + hm*8];
    f32x4 ini = {fcbv, fcbv, fcbv, fcbv};
    d2[g] = __builtin_amdgcn_mfma_f32_16x16x32_bf16(a2, b2, ini, 0,0,0);
  }
  __syncthreads();

  if(tcol<12){
    float rwa[4], rba[4];
    #pragma unroll
    for(int r=0;r<4;r++){ int c=w*16+hq*4+r; rwa[r]=rw[c]; rba[r]=rb[c]; }
    #pragma unroll
    for(int g=0; g<8; g++){
      float xv=xres[g][tcol];
      #pragma unroll
      for(int r=0;r<4;r++){
        int c=w*16+hq*4+r;
        float tv = fmaxf(d2[g][r], 0.f);
        float xr = xv*rwa[r]+rba[r];
        U.XP[g][c*12+tcol] = fmaxf(xr+tv, 0.f);
      }
    }
  }
  __syncthreads();

  if(tid<192){
    int p=tid>>1, h=tid&1;
    int g=p/12, t=p-(p/12)*12;
    float s=0.f;
    for(int c=h*32;c<h*32+32;c++) s+=U.XP[g][c*12+t];
    s += __shfl_xor(s,1,64);
    float mu=s*(1.f/64.f);
    float q=0.f;
    for(int c=h*32;c<h*32+32;c++){float d=U.XP[g][c*12+t]-mu;q+=d*d;}
    q += __shfl_xor(q,1,64);
    if(h==0){ mu8[g][t]=mu; rs8[g][t]=rsqrtf(q*(1.f/64.f)+EPS); }
  }
  __syncthreads();
  for(int o=tid;o<1536;o+=256){
    int g=o/192; int q4=o-g*192;
    int c=q4/3; int tb=(q4-c*3)*4;
    float4 vv = *(const float4*)&U.XP[g][c*12+tb];
    float gl=gln[c], bl=bln[c];
    float4 ov;
    ov.x=(vv.x-mu8[g][tb+0])*rs8[g][tb+0]*gl+bl;
    ov.y=(vv.y-mu8[g][tb+1])*rs8[g][tb+1]*gl+bl;
    ov.z=(vv.z-mu8[g][tb+2])*rs8[g][tb+2]*gl+bl;
    ov.w=(vv.w-mu8[g][tb+3])*rs8[g][tb+3]*gl+bl;
    *(float4*)&out[(long)(bn0+g)*768 + c*12 + tb] = ov;
  }
}

// ---------------- launch ----------------
extern "C" void kernel_launch(void* const* d_in, const int* in_sizes, int n_in,
                              void* d_out, int out_size, void* d_ws, size_t ws_size,
                              hipStream_t stream){
  const float* x    =(const float*)d_in[0];
  const float* res  =(const float*)d_in[1];
  const float* posT =(const float*)d_in[2];
  const float* gT   =(const float*)d_in[3];
  const float* bT   =(const float*)d_in[4];
  const float* wq   =(const float*)d_in[5];
  const float* wk   =(const float*)d_in[6];
  const float* wv   =(const float*)d_in[7];
  const float* fcW  =(const float*)d_in[8];
  const float* prw  =(const float*)d_in[9];
  const float* prb  =(const float*)d_in[10];
  const float* posS =(const float*)d_in[11];
  const float* gS   =(const float*)d_in[12];
  const float* bS   =(const float*)d_in[13];
  const float* swq  =(const float*)d_in[14];
  const float* swk  =(const float*)d_in[15];
  const float* cheb =(const float*)d_in[16];
  const float* adj  =(const float*)d_in[17];
  const float* cmask=(const float*)d_in[18];
  const float* theta=(const float*)d_in[19];
  const float* g3w=(const float*)d_in[20]; const float* g3b=(const float*)d_in[21];
  const float* g5w=(const float*)d_in[22]; const float* g5b=(const float*)d_in[23];
  const float* g7w=(const float*)d_in[24]; const float* g7b=(const float*)d_in[25];
  const float* fcw=(const float*)d_in[26]; const float* fcb=(const float*)d_in[27];
  const float* rw =(const float*)d_in[28]; const float* rb =(const float*)d_in[29];
  const float* gln=(const float*)d_in[30]; const float* bln=(const float*)d_in[31];

  float* outp=(float*)d_out;
  float* scores = outp + 12582912;

  float* wsf=(float*)d_ws;
  float* TEmx = wsf;                          // 196608 f
  float* qkv  = TEmx + 196608;                // 55296 f
  float* TATpre = qkv + 55296;                // 196608 f
  unsigned short* SEb = (unsigned short*)(TATpre + 196608);      // 4194304 f
  unsigned short* SQb = (unsigned short*)((float*)SEb + 4194304); // 786432 f
  unsigned short* SKb = (unsigned short*)((float*)SQb + 786432);  // 786432 f
  unsigned* mcT = (unsigned*)((float*)SKb + 786432);              // 3145728 f
  float* rhsT  = (float*)mcT + 3145728;                           // 589824 f
  unsigned short* Apack = (unsigned short*)(rhsT + 589824);       // 122880 u16
  unsigned short* Wpack = Apack + 122880;                         // 98304 u16
  unsigned short* Wpack2 = Wpack + 98304;                         // 294912 u16
  unsigned short* TEb = Wpack2 + 294912;                          // 196608 u16
  unsigned short* fcwB = TEb + 196608;                            // 512 u16
  unsigned short* ctxb = fcwB + 512;                              // 18432 u16
  unsigned short* fcWB2 = ctxb + 18432;                           // 98304 u16
  float* muT = (float*)(fcWB2 + 98304);                           // 192 f
  float* rsT = muT + 192;                                         // 192 f

  kbp_prep<<<dim3(1069),dim3(256),0,stream>>>(adj,cmask,cheb,mcT,
                                              g3w,g5w,g7w,swq,swk,wq,wk,wv,fcw,fcW,
                                              Apack,Wpack,Wpack2,fcwB,fcWB2);
  k1_embedT<<<dim3(192),dim3(256),0,stream>>>(x,posT,gT,bT,TEmx,TEb);
  k2_qkv<<<dim3(216),dim3(256),0,stream>>>(TEb,Wpack2,qkv);
  k3_attn<<<dim3(48),dim3(256),0,stream>>>(qkv,res,scores,ctxb);
  k4a_mm<<<dim3(192),dim3(256),0,stream>>>(ctxb,fcWB2,TEmx,TATpre);
  k4b_stats<<<dim3(192),dim3(256),0,stream>>>(TATpre,muT,rsT);
  k5_semx<<<dim3(2048),dim3(256),0,stream>>>(TATpre,muT,rsT,prw,prb,posS,gS,bS,SEb);
  k6_sqk<<<dim3(1024),dim3(256),0,stream>>>(SEb,Wpack,SQb,SKb);
  k7_spatial<<<dim3(768),dim3(256),0,stream>>>(SQb,SKb,mcT,x,rhsT);
  k9_final<<<dim3(2048),dim3(256),0,stream>>>(rhsT,theta,Apack,fcwB,g3b,g5b,g7b,
                                              fcb,rw,rb,gln,bln,x,outp);
}

// Round 15
// 141.283 us; speedup vs baseline: 1.0350x; 1.0350x over previous
//
#include <hip/hip_runtime.h>
#include <hip/hip_fp16.h>

#define EPS 1e-5f

typedef float f32x4 __attribute__((ext_vector_type(4)));
typedef short bf16x8 __attribute__((ext_vector_type(8)));
typedef short bf16x4 __attribute__((ext_vector_type(4)));

__device__ __forceinline__ unsigned short f2b(float f){
  unsigned u=__float_as_uint(f);
  return (unsigned short)((u + 0x7fffu + ((u>>16)&1u))>>16);
}
__device__ __forceinline__ float b2f(unsigned short h){
  return __uint_as_float(((unsigned)h)<<16);
}

// ---------------- helpers ----------------
__device__ __forceinline__ float blockSum256(float v, float* red){
  #pragma unroll
  for(int o=32;o>0;o>>=1) v += __shfl_down(v,o,64);
  int wid = threadIdx.x>>6;
  if((threadIdx.x&63)==0) red[wid]=v;
  __syncthreads();
  if(threadIdx.x==0) red[0]=red[0]+red[1]+red[2]+red[3];
  __syncthreads();
  float r = red[0];
  __syncthreads();
  return r;
}

// ---------------- KBP: fused prep — mcT transpose (blocks 0..767) + weight packing (768..1068) ----
__global__ __launch_bounds__(256) void kbp_prep(const float* __restrict__ adj, const float* __restrict__ cmask,
    const float* __restrict__ cheb, unsigned* __restrict__ mcT,
    const float* __restrict__ g3w, const float* __restrict__ g5w,
    const float* __restrict__ g7w, const float* __restrict__ swq, const float* __restrict__ swk,
    const float* __restrict__ wq, const float* __restrict__ wk, const float* __restrict__ wv,
    const float* __restrict__ fcw, const float* __restrict__ fcW,
    unsigned short* __restrict__ Apack, unsigned short* __restrict__ Wpack,
    unsigned short* __restrict__ Wpack2, unsigned short* __restrict__ fcwB,
    unsigned short* __restrict__ fcWB2){
  int tid=threadIdx.x;
  if(blockIdx.x<768){
    int blk=blockIdx.x;                 // k*256 + tn*16 + tm
    int k=blk>>8; int rem=blk&255; int tn=rem>>4, tm=rem&15;
    __shared__ unsigned tile[64][65];
    const float* chk = cheb + k*1048576;
    const float* cmk = cmask + k*1048576;
    for(int i=tid;i<4096;i+=256){
      int ln=i>>6, lm=i&63;
      int n=tn*64+ln, m=tm*64+lm;
      int nm=n*1024+m;
      tile[ln][lm] = (((unsigned)f2b(chk[nm]))<<16) | (unsigned)f2b(adj[nm]*cmk[nm]);
    }
    __syncthreads();
    unsigned* dst = mcT + k*1048576;
    for(int i=tid;i<4096;i+=256){
      int lm=i>>6, ln=i&63;
      dst[(tm*64+lm)*1024 + tn*64+ln] = tile[ln][lm];
    }
    return;
  }
  int idx = (blockIdx.x-768)*256+tid;
  if(idx<15360){                                   // Apack (conv A-frags, bf16)
    int frag=idx>>6, lane=idx&63;
    int rt, s, kappa; const float* W;
    if(frag<48){ rt=frag/6; s=frag-rt*6; kappa=3; W=g3w; }
    else if(frag<128){ int f=frag-48; rt=f/10; s=f-rt*10; kappa=5; W=g5w; }
    else { int f=frag-128; rt=f/14; s=f-rt*14; kappa=7; W=g7w; }
    int c = rt*16 + (lane&15);
    int dt = s>>1, ic0=(s&1)*32 + (lane>>4)*8;
    #pragma unroll
    for(int j=0;j<8;j++) Apack[idx*8+j]=f2b(W[(c*64+ic0+j)*kappa + dt]);
  } else if(idx<27648){                            // Wpack (swq/swk B-frags)
    int id2=idx-15360;
    int frag=id2>>6, lane=id2&63;
    int ct=frag>>4, ks=frag&15;
    const float* W = (ct<6)? swq : swk;
    int c = ((ct<6)? ct : ct-6)*16 + (lane&15);
    int k0 = ks*32 + (lane>>4)*8;
    #pragma unroll
    for(int j=0;j<8;j++) Wpack[id2*8+j]=f2b(W[(k0+j)*96 + c]);
  } else if(idx<64512){                            // Wpack2 (wq|wk|wv B-frags)
    int id2=idx-27648;
    int frag=id2>>6, lane=id2&63;
    int ct=frag>>5, ks=frag&31;
    int cg = ct*16 + (lane&15);
    const float* W; int c;
    if(cg<96){ W=wq; c=cg; } else if(cg<192){ W=wk; c=cg-96; } else { W=wv; c=cg-192; }
    int k0 = ks*32 + (lane>>4)*8;
    #pragma unroll
    for(int j=0;j<8;j++) Wpack2[id2*8+j]=f2b(W[(k0+j)*96 + c]);
  } else if(idx<64576){                            // fcwB (bf16)
    int lane=idx-64512;
    int t=lane&15, hq=lane>>4;
    #pragma unroll
    for(int j=0;j<8;j++){
      int tau=hq*8+j;
      fcwB[lane*8+j] = (tau<24 && t<12) ? f2b(fcw[tau*12+t]) : (unsigned short)0;
    }
  } else if(idx<76864){                            // fcWB2 (fcW B-frags: 64 ct x 3 ks)
    int id3=idx-64576;
    int frag=id3>>6, lane=id3&63;
    int ct=frag/3, ks=frag-ct*3;
    int c = ct*16 + (lane&15);
    int k0 = ks*32 + (lane>>4)*8;
    #pragma unroll
    for(int j=0;j<8;j++) fcWB2[id3*8+j]=f2b(fcW[(k0+j)*1024 + c]);
  }
}

// ---------------- K1: EmbedT (fp32 + bf16 outputs) ----------------
__global__ __launch_bounds__(256) void k1_embedT(const float* __restrict__ x, const float* __restrict__ posT,
    const float* __restrict__ gT, const float* __restrict__ bT, float* __restrict__ TEmx,
    unsigned short* __restrict__ TEb){
  int bt=blockIdx.x; int b=bt/12, t=bt-b*12;
  int tid=threadIdx.x;
  __shared__ float red[4];
  float v[4]; float s=0.f;
  #pragma unroll
  for(int i=0;i<4;i++){ int n=tid+i*256; v[i]=x[(b*1024+n)*12+t]+posT[t*1024+n]; s+=v[i]; }
  s = blockSum256(s, red);
  float mu = s*(1.f/1024.f);
  float q=0.f;
  #pragma unroll
  for(int i=0;i<4;i++){ float d=v[i]-mu; q+=d*d; }
  q = blockSum256(q, red);
  float rstd = rsqrtf(q*(1.f/1024.f)+EPS);
  #pragma unroll
  for(int i=0;i<4;i++){
    int n=tid+i*256;
    float val=(v[i]-mu)*rstd*gT[n]+bT[n];
    TEmx[bt*1024+n]=val;
    TEb[bt*1024+n]=f2b(val);
  }
}

// ---------------- K2: QKV via MFMA split-K GEMM ----------------
__global__ __launch_bounds__(256) void k2_qkv(const unsigned short* __restrict__ TEb,
    const unsigned short* __restrict__ Wpack2, float* __restrict__ qkv){
  int tid=threadIdx.x; int w=tid>>6, lane=tid&63;
  const int hi=lane>>4, lo=lane&15;
  const int rt=blockIdx.x/18, ct=blockIdx.x-rt*18;
  __shared__ float red[4][16][16];
  f32x4 acc={0.f,0.f,0.f,0.f};
  #pragma unroll
  for(int s=0;s<8;s++){
    int ks=w*8+s;
    bf16x8 af = *(const bf16x8*)&TEb[(rt*16+lo)*1024 + ks*32 + hi*8];
    bf16x8 bf = *(const bf16x8*)&Wpack2[((ct*32+ks)<<9) + lane*8];
    acc = __builtin_amdgcn_mfma_f32_16x16x32_bf16(af, bf, acc, 0,0,0);
  }
  #pragma unroll
  for(int r=0;r<4;r++) red[w][hi*4+r][lo]=acc[r];
  __syncthreads();
  int r16=tid>>4, c16=tid&15;
  float s = red[0][r16][c16]+red[1][r16][c16]+red[2][r16][c16]+red[3][r16][c16];
  qkv[(rt*16+r16)*288 + ct*16 + c16] = s;
}

// ---------------- K3: temporal attn, 48 blocks (b,h) ----------------
__global__ __launch_bounds__(256) void k3_attn(const float* __restrict__ qkv, const float* __restrict__ res_att,
    float* __restrict__ scores_out, unsigned short* __restrict__ ctxb){
  int bh=blockIdx.x; int b=bh/3, h=bh-(bh/3)*3;
  int tid=threadIdx.x;
  __shared__ float sS[144];
  __shared__ float sA[144];
  if(tid<144){
    int q=tid/12;
    const float* Qr=&qkv[(b*12+q)*288 + h*32];
    const float* Kr=&qkv[(b*12+(tid-q*12))*288 + 96 + h*32];
    float acc=0.f;
    #pragma unroll
    for(int d=0;d<32;d++) acc+=Qr[d]*Kr[d];
    acc = acc*0.17677669529663687f + res_att[bh*144 + tid];
    sS[tid]=acc;
    scores_out[bh*144 + tid]=acc;
  }
  __syncthreads();
  if(tid<12){
    int k2=tid;
    float mx=-1e30f;
    for(int q=0;q<12;q++) mx=fmaxf(mx,sS[q*12+k2]);
    float sum=0.f;
    for(int q=0;q<12;q++){ float e=__expf(sS[q*12+k2]-mx); sA[q*12+k2]=e; sum+=e; }
    float inv=1.f/sum;
    for(int q=0;q<12;q++) sA[q*12+k2]*=inv;
  }
  __syncthreads();
  for(int o=tid;o<384;o+=256){
    int q=o>>5, d=o&31;
    float acc=0.f;
    #pragma unroll
    for(int k2=0;k2<12;k2++) acc += sA[q*12+k2]*qkv[(b*12+k2)*288+192+h*32+d];
    ctxb[(b*12+q)*96 + h*32 + d]=f2b(acc);
  }
}

// ---------------- K4a: TATpre = ctx@fcW + TEmx via MFMA ----------------
__global__ __launch_bounds__(256) void k4a_mm(const unsigned short* __restrict__ ctxb,
    const unsigned short* __restrict__ fcWB2, const float* __restrict__ TEmx,
    float* __restrict__ TATpre){
  int tid=threadIdx.x; int w=tid>>6, lane=tid&63;
  const int hi=lane>>4, lo=lane&15;
  const int rt=blockIdx.x>>4, cg=blockIdx.x&15;
  const int ct=cg*4+w;
  f32x4 acc={0.f,0.f,0.f,0.f};
  #pragma unroll
  for(int ks=0;ks<3;ks++){
    bf16x8 af = *(const bf16x8*)&ctxb[(rt*16+lo)*96 + ks*32 + hi*8];
    bf16x8 bf = *(const bf16x8*)&fcWB2[((ct*3+ks)<<9) + lane*8];
    acc = __builtin_amdgcn_mfma_f32_16x16x32_bf16(af, bf, acc, 0,0,0);
  }
  #pragma unroll
  for(int r=0;r<4;r++){
    int row = rt*16 + hi*4 + r;
    int coln = ct*16 + lo;
    TATpre[row*1024+coln] = acc[r] + TEmx[row*1024+coln];
  }
}

// ---------------- K4b: per-row LN stats ----------------
__global__ __launch_bounds__(256) void k4b_stats(const float* __restrict__ TATpre,
    float* __restrict__ muT, float* __restrict__ rsT){
  int bt=blockIdx.x; int tid=threadIdx.x;
  __shared__ float red[4];
  const float* row=&TATpre[bt*1024];
  float a0=row[tid], a1=row[tid+256], a2=row[tid+512], a3=row[tid+768];
  float s=a0+a1+a2+a3;
  s=blockSum256(s,red);
  float mu=s*(1.f/1024.f);
  float q=(a0-mu)*(a0-mu)+(a1-mu)*(a1-mu)+(a2-mu)*(a2-mu)+(a3-mu)*(a3-mu);
  q=blockSum256(q,red);
  if(tid==0){ muT[bt]=mu; rsT[bt]=rsqrtf(q*(1.f/1024.f)+EPS); }
}

// ---------------- K5: SEmx, 8 rows/block; LN applied on tv load ----------------
__global__ __launch_bounds__(256) void k5_semx(const float* __restrict__ TATpre,
    const float* __restrict__ muT, const float* __restrict__ rsT,
    const float* __restrict__ pre_w,
    const float* __restrict__ pre_b, const float* __restrict__ posS, const float* __restrict__ gS,
    const float* __restrict__ bS, unsigned short* __restrict__ SEb){
  int bn0=blockIdx.x*8; int b=bn0>>10, n0=bn0&1023; int tid=threadIdx.x;
  __shared__ float tv[12][8];
  __shared__ float ps[8][264];
  __shared__ float pq[8][264];
  __shared__ float mur[8], rsr[8];
  if(tid<96){
    int r=tid&7, t=tid>>3;
    int bt=b*12+t;
    tv[t][r]=(TATpre[bt*1024+n0+r]-muT[bt])*rsT[bt];
  }
  __syncthreads();
  const int d0=tid, d1=tid+256;
  float w0[12], w1[12];
  {
    const float4* p0=(const float4*)&pre_w[d0*12];
    float4 a=p0[0], bb=p0[1], c=p0[2];
    w0[0]=a.x;w0[1]=a.y;w0[2]=a.z;w0[3]=a.w; w0[4]=bb.x;w0[5]=bb.y;w0[6]=bb.z;w0[7]=bb.w;
    w0[8]=c.x;w0[9]=c.y;w0[10]=c.z;w0[11]=c.w;
    const float4* p1=(const float4*)&pre_w[d1*12];
    float4 d=p1[0], e=p1[1], f=p1[2];
    w1[0]=d.x;w1[1]=d.y;w1[2]=d.z;w1[3]=d.w; w1[4]=e.x;w1[5]=e.y;w1[6]=e.z;w1[7]=e.w;
    w1[8]=f.x;w1[9]=f.y;w1[10]=f.z;w1[11]=f.w;
  }
  float pb0=pre_b[d0], pb1=pre_b[d1];
  float v0[8], v1[8];
  #pragma unroll
  for(int r=0;r<8;r++){
    float acc0=pb0 + posS[(n0+r)*512+d0];
    float acc1=pb1 + posS[(n0+r)*512+d1];
    #pragma unroll
    for(int t=0;t<12;t++){ float tvv=tv[t][r]; acc0+=tvv*w0[t]; acc1+=tvv*w1[t]; }
    v0[r]=acc0; v1[r]=acc1;
    ps[r][tid]=acc0+acc1;
    pq[r][tid]=acc0*acc0+acc1*acc1;
  }
  __syncthreads();
  {
    int row=tid>>5, l32=tid&31;
    float s=0.f, q=0.f;
    #pragma unroll
    for(int j=0;j<8;j++){ s+=ps[row][l32+j*32]; q+=pq[row][l32+j*32]; }
    #pragma unroll
    for(int o=16;o>=1;o>>=1){ s+=__shfl_xor(s,o,64); q+=__shfl_xor(q,o,64); }
    if(l32==0){
      float mu=s*(1.f/512.f);
      float var=q*(1.f/512.f)-mu*mu;
      mur[row]=mu; rsr[row]=rsqrtf(var+EPS);
    }
  }
  __syncthreads();
  float g0=gS[d0], b0v=bS[d0], g1=gS[d1], b1v=bS[d1];
  #pragma unroll
  for(int r=0;r<8;r++){
    float mu=mur[r], rs=rsr[r];
    SEb[(bn0+r)*512 + d0] = f2b((v0[r]-mu)*rs*g0+b0v);
    SEb[(bn0+r)*512 + d1] = f2b((v1[r]-mu)*rs*g1+b1v);
  }
}

// ---------------- K6: SQ/SK via MFMA GEMM, 16 rows/block; af prefetch ----------------
__global__ __launch_bounds__(256) void k6_sqk(const unsigned short* __restrict__ SEb,
    const unsigned short* __restrict__ Wpack,
    unsigned short* __restrict__ SQb, unsigned short* __restrict__ SKb){
  int tid=threadIdx.x; int w=tid>>6, lane=tid&63;
  const int hi=lane>>4, lo=lane&15;
  const int row0 = blockIdx.x*16;
  f32x4 acc[3];
  #pragma unroll
  for(int i=0;i<3;i++){ acc[i][0]=0.f; acc[i][1]=0.f; acc[i][2]=0.f; acc[i][3]=0.f; }
  const unsigned short* arow = &SEb[(row0+lo)*512 + hi*8];
  bf16x8 afc = *(const bf16x8*)&arow[0];
  #pragma unroll
  for(int ks=0;ks<16;ks++){
    bf16x8 afn;
    if(ks<15) afn = *(const bf16x8*)&arow[(ks+1)*32];
    #pragma unroll
    for(int j=0;j<3;j++){
      int ct = w*3+j;
      bf16x8 bf = *(const bf16x8*)&Wpack[((ct*16+ks)<<9) + lane*8];
      acc[j] = __builtin_amdgcn_mfma_f32_16x16x32_bf16(afc, bf, acc[j], 0,0,0);
    }
    if(ks<15) afc = afn;
  }
  #pragma unroll
  for(int j=0;j<3;j++){
    int ct = w*3+j;
    int c96 = ((ct<6)? ct : ct-6)*16 + lo;
    int kq = c96>>5, d = c96&31;
    unsigned short* dst = (ct<6)? SQb : SKb;
    #pragma unroll
    for(int r=0;r<4;r++){
      int n = row0 + hi*4 + r;
      int b = n>>10, nl = n&1023;
      dst[((b*3+kq)*1024+nl)*32 + d] = f2b(acc[j][r]);
    }
  }
}

// ---------------- K7: whole-x LDS stage; prefetch (no setprio) ----------------
#define SCALE7 0.17677669529663687f
__global__ __launch_bounds__(256) void k7_spatial(const unsigned short* __restrict__ SQb,
    const unsigned short* __restrict__ SKb, const unsigned* __restrict__ mcT,
    const float* __restrict__ x, float* __restrict__ rhsT){
  const int blk0=blockIdx.x;
  const int blk=(blk0&7)*96 + (blk0>>3);      // XCD-chunked: 768 = 8*96, bijective
  const int mt=blk&15, bk=blk>>4;
  const int k=bk%3, b=bk/3;
  const int m0=mt*64;
  const int tid=threadIdx.x;
  const int w=tid>>6, lane=tid&63, g=lane>>4, col=lane&15;

  __shared__ unsigned short xs[16*1024];

  const float* xb = x + b*12288;
  for(int i=tid;i<2048;i+=256) ((unsigned*)xs)[12*512 + i] = 0u;
  for(int i=tid;i<12288;i+=256){
    int n=i/12, t=i-n*12;
    xs[t*1024 + (n ^ ((t&7)<<3))] = f2b(xb[i]);
  }
  __syncthreads();

  const int m_glob = m0 + w*16 + col;
  bf16x8 bfrag = *(const bf16x8*)&SKb[((bk<<10)+m_glob)*32 + g*8];

  f32x4 O = {0.f,0.f,0.f,0.f};
  float mrun=-1e30f, lrun=0.f;

  const unsigned* mrow = mcT + k*1048576 + m_glob*1024;
  const unsigned short* sqbase = &SQb[((bk<<10)+col)*32 + g*8];
  const int swz = (col&7)<<3;

  uint4 mvc[8]; bf16x8 afc[8];
  #pragma unroll
  for(int nt=0;nt<8;nt++){
    mvc[nt] = *(const uint4*)&mrow[nt*16 + g*4];
    afc[nt] = *(const bf16x8*)&sqbase[(nt*16)*32];
  }

  #pragma unroll
  for(int ch=0; ch<8; ++ch){
    const int n0 = ch<<7;
    uint4 mvn[8]; bf16x8 afn[8];
    #pragma unroll
    for(int nt=0;nt<8;nt++){
      if(ch<7){
        mvn[nt] = *(const uint4*)&mrow[n0+128 + nt*16 + g*4];
        afn[nt] = *(const bf16x8*)&sqbase[(n0+128 + nt*16)*32];
      }
    }

    f32x4 acc[8];
    #pragma unroll
    for(int nt=0;nt<8;nt++){
      f32x4 z = {0.f,0.f,0.f,0.f};
      acc[nt] = __builtin_amdgcn_mfma_f32_16x16x32_bf16(afc[nt], bfrag, z, 0,0,0);
    }
    float cmax = -1e30f;
    #pragma unroll
    for(int nt=0;nt<8;nt++){
      #pragma unroll
      for(int r=0;r<4;r++){
        unsigned mv = (r==0)?mvc[nt].x:((r==1)?mvc[nt].y:((r==2)?mvc[nt].z:mvc[nt].w));
        float s = acc[nt][r]*SCALE7 + __uint_as_float(mv<<16);
        acc[nt][r]=s;
        cmax=fmaxf(cmax,s);
      }
    }
    cmax = fmaxf(cmax, __shfl_xor(cmax,16,64));
    cmax = fmaxf(cmax, __shfl_xor(cmax,32,64));
    float mnew = fmaxf(mrun, cmax);
    float alpha = __expf(mrun - mnew);
    float lsum = 0.f;
    unsigned short pb[8][4];
    #pragma unroll
    for(int nt=0;nt<8;nt++){
      #pragma unroll
      for(int r=0;r<4;r++){
        unsigned mv = (r==0)?mvc[nt].x:((r==1)?mvc[nt].y:((r==2)?mvc[nt].z:mvc[nt].w));
        float e = __expf(acc[nt][r] - mnew);
        lsum += e;
        pb[nt][r] = f2b(e * __uint_as_float(mv & 0xffff0000u));
      }
    }
    lsum += __shfl_xor(lsum,16,64);
    lsum += __shfl_xor(lsum,32,64);
    lrun = lrun*alpha + lsum;
    mrun = mnew;
    O[0]*=alpha; O[1]*=alpha; O[2]*=alpha; O[3]*=alpha;

    #pragma unroll
    for(int c=0;c<4;c++){
      bf16x8 pf;
      #pragma unroll
      for(int j=0;j<4;j++){ pf[j]=(short)pb[2*c][j]; pf[j+4]=(short)pb[2*c+1][j]; }
      int nlo = n0 + c*32 + g*4;
      bf16x4 lo = *(const bf16x4*)&xs[col*1024 + (nlo ^ swz)];
      bf16x4 hi = *(const bf16x4*)&xs[col*1024 + ((nlo+16) ^ swz)];
      bf16x8 ax;
      #pragma unroll
      for(int j=0;j<4;j++){ ax[j]=lo[j]; ax[j+4]=hi[j]; }
      O = __builtin_amdgcn_mfma_f32_16x16x32_bf16(ax, pf, O, 0,0,0);
    }
    #pragma unroll
    for(int nt=0;nt<8;nt++){
      if(ch<7){ mvc[nt]=mvn[nt]; afc[nt]=afn[nt]; }
    }
  }
  float inv = 1.f/lrun;
  #pragma unroll
  for(int r=0;r<4;r++){
    int t = g*4+r;
    if(t<12) rhsT[((bk*12+t)<<10) + m_glob] = O[r]*inv;
  }
}

// ---------------- K9: conv MFMA (setprio) -> gated LDS -> fc MFMA -> residual+LN ----
__global__ __launch_bounds__(256) void k9_final(const float* __restrict__ rhsT, const float* __restrict__ theta,
    const unsigned short* __restrict__ Apack, const unsigned short* __restrict__ fcwB,
    const float* __restrict__ g3b, const float* __restrict__ g5b, const float* __restrict__ g7b,
    const float* __restrict__ fcb,
    const float* __restrict__ rw, const float* __restrict__ rb,
    const float* __restrict__ gln, const float* __restrict__ bln,
    const float* __restrict__ x, float* __restrict__ out){
  int bn0=blockIdx.x*8;
  int tid=threadIdx.x;
  const int b=bn0>>10, n0=bn0&1023;

  __shared__ struct { unsigned short Xl[12*8*64]; float rstage[3][12][8]; } P0;
  __shared__ union {
    unsigned short Gl[4*16*8*24];   // [wave][c_loc][g'][tau]
    float XP[8][772];
  } U;
  __shared__ float xres[8][12];
  __shared__ float mu8[8][12], rs8[8][12];

  for(int i=tid;i<288;i+=256){
    int kk=i/96; int rem=i-kk*96; int t=rem>>3; int g=rem&7;
    P0.rstage[kk][t][g]=rhsT[((b*3+kk)*12+t)*1024 + n0 + g];
  }
  for(int i=tid;i<96;i+=256){ int g=i/12, t=i-(i/12)*12; xres[g][t]=x[(bn0+g)*12+t]; }
  __syncthreads();

  {
    int g=tid>>5, icp=tid&31;
    float th0[3], th1[3];
    #pragma unroll
    for(int kk=0;kk<3;kk++){ th0[kk]=theta[kk*64+2*icp]; th1[kk]=theta[kk*64+2*icp+1]; }
    #pragma unroll
    for(int t=0;t<12;t++){
      float r0=P0.rstage[0][t][g], r1=P0.rstage[1][t][g], r2=P0.rstage[2][t][g];
      float a0=fmaxf(r0*th0[0]+r1*th0[1]+r2*th0[2],0.f);
      float a1=fmaxf(r0*th1[0]+r1*th1[1]+r2*th1[2],0.f);
      unsigned pack = (((unsigned)f2b(a1))<<16)|(unsigned)f2b(a0);
      *(unsigned*)((char*)P0.Xl + ((t*8+g)<<7) + ((icp*4) ^ (g<<4))) = pack;
    }
  }
  __syncthreads();

  const int w=tid>>6, lane=tid&63, halfk=lane>>4, colq=lane&15;
  const int gg=colq&7, tau2=colq>>3;
  const int ca = w*16 + halfk*4;
  const char* xlb = (const char*)P0.Xl;
  unsigned short* Glw = &U.Gl[w*3072];

  #define GATE_STORE(ACCA, ACCB, TB) { \
    _Pragma("unroll") \
    for(int r=0;r<4;r++){ \
      float ya=(ACCA)[r], yb=(ACCB)[r]; \
      float e2=__expf(2.f*ya), eb=__expf(yb); \
      float gval=(e2-1.f)*eb*__frcp_rn((e2+1.f)*(eb+1.f)); \
      int c_loc=halfk*4+r; \
      Glw[c_loc*192 + ((gg ^ (c_loc&7))*24) + (TB)+tau2] = f2b(gval); \
    } }

  // ---- group kappa=3 (6 K-steps, 5 col-tiles) ----
  {
    f32x4 acA[5], acB[5];
    #pragma unroll
    for(int j=0;j<5;j++)
      #pragma unroll
      for(int r=0;r<4;r++){ acA[j][r]=g3b[ca+r]; acB[j][r]=g3b[64+ca+r]; }
    const unsigned short* ap0=&Apack[((w  )*6)*512 + lane*8];
    const unsigned short* ap1=&Apack[((w+4)*6)*512 + lane*8];
    bf16x8 a0c=*(const bf16x8*)&ap0[0];
    bf16x8 a1c=*(const bf16x8*)&ap1[0];
    #pragma unroll
    for(int s=0;s<6;s++){
      bf16x8 a0n, a1n;
      if(s<5){ a0n=*(const bf16x8*)&ap0[(s+1)*512]; a1n=*(const bf16x8*)&ap1[(s+1)*512]; }
      int dt=s>>1;
      int sl = ((((s&1)*32 + halfk*8)*2) ^ (gg<<4));
      __builtin_amdgcn_s_setprio(1);
      #pragma unroll
      for(int j=0;j<5;j++){
        int t=2*j+tau2+dt;
        bf16x8 bf = *(const bf16x8*)(xlb + ((t*8+gg)<<7) + sl);
        acA[j] = __builtin_amdgcn_mfma_f32_16x16x32_bf16(a0c, bf, acA[j], 0,0,0);
        acB[j] = __builtin_amdgcn_mfma_f32_16x16x32_bf16(a1c, bf, acB[j], 0,0,0);
      }
      __builtin_amdgcn_s_setprio(0);
      if(s<5){ a0c=a0n; a1c=a1n; }
    }
    #pragma unroll
    for(int j=0;j<5;j++) GATE_STORE(acA[j], acB[j], 2*j)
  }
  // ---- group kappa=5 (10 K-steps, 4 col-tiles) ----
  {
    f32x4 acA[4], acB[4];
    #pragma unroll
    for(int j=0;j<4;j++)
      #pragma unroll
      for(int r=0;r<4;r++){ acA[j][r]=g5b[ca+r]; acB[j][r]=g5b[64+ca+r]; }
    const unsigned short* ap0=&Apack[(48 + (w  )*10)*512 + lane*8];
    const unsigned short* ap1=&Apack[(48 + (w+4)*10)*512 + lane*8];
    bf16x8 a0c=*(const bf16x8*)&ap0[0];
    bf16x8 a1c=*(const bf16x8*)&ap1[0];
    #pragma unroll
    for(int s=0;s<10;s++){
      bf16x8 a0n, a1n;
      if(s<9){ a0n=*(const bf16x8*)&ap0[(s+1)*512]; a1n=*(const bf16x8*)&ap1[(s+1)*512]; }
      int dt=s>>1;
      int sl = ((((s&1)*32 + halfk*8)*2) ^ (gg<<4));
      __builtin_amdgcn_s_setprio(1);
      #pragma unroll
      for(int j=0;j<4;j++){
        int t=2*j+tau2+dt;
        bf16x8 bf = *(const bf16x8*)(xlb + ((t*8+gg)<<7) + sl);
        acA[j] = __builtin_amdgcn_mfma_f32_16x16x32_bf16(a0c, bf, acA[j], 0,0,0);
        acB[j] = __builtin_amdgcn_mfma_f32_16x16x32_bf16(a1c, bf, acB[j], 0,0,0);
      }
      __builtin_amdgcn_s_setprio(0);
      if(s<9){ a0c=a0n; a1c=a1n; }
    }
    #pragma unroll
    for(int j=0;j<4;j++) GATE_STORE(acA[j], acB[j], 10+2*j)
  }
  // ---- group kappa=7 (14 K-steps, 3 col-tiles) ----
  {
    f32x4 acA[3], acB[3];
    #pragma unroll
    for(int j=0;j<3;j++)
      #pragma unroll
      for(int r=0;r<4;r++){ acA[j][r]=g7b[ca+r]; acB[j][r]=g7b[64+ca+r]; }
    const unsigned short* ap0=&Apack[(128 + (w  )*14)*512 + lane*8];
    const unsigned short* ap1=&Apack[(128 + (w+4)*14)*512 + lane*8];
    bf16x8 a0c=*(const bf16x8*)&ap0[0];
    bf16x8 a1c=*(const bf16x8*)&ap1[0];
    #pragma unroll
    for(int s=0;s<14;s++){
      bf16x8 a0n, a1n;
      if(s<13){ a0n=*(const bf16x8*)&ap0[(s+1)*512]; a1n=*(const bf16x8*)&ap1[(s+1)*512]; }
      int dt=s>>1;
      int sl = ((((s&1)*32 + halfk*8)*2) ^ (gg<<4));
      __builtin_amdgcn_s_setprio(1);
      #pragma unroll
      for(int j=0;j<3;j++){
        int t=2*j+tau2+dt;
        bf16x8 bf = *(const bf16x8*)(xlb + ((t*8+gg)<<7) + sl);
        acA[j] = __builtin_amdgcn_mfma_f32_16x16x32_bf16(a0c, bf, acA[j], 0,0,0);
        acB[j] = __builtin_amdgcn_mfma_f32_16x16x32_bf16(a1c, bf, acB[j], 0,0,0);
      }
      __builtin_amdgcn_s_setprio(0);
      if(s<13){ a0c=a0n; a1c=a1n; }
    }
    #pragma unroll
    for(int j=0;j<3;j++) GATE_STORE(acA[j], acB[j], 18+2*j)
  }
  #undef GATE_STORE

  // ---- fc via MFMA ----
  const int tcol = lane&15, hq = lane>>4;
  const int hm = (hq==3)? 0 : hq;
  bf16x8 b2 = *(const bf16x8*)&fcwB[lane*8];
  float fcbv = (tcol<12)? fcb[tcol] : 0.f;
  f32x4 d2[8];
  #pragma unroll
  for(int g=0; g<8; g++){
    bf16x8 a2 = *(const bf16x8*)&Glw[tcol*192 + ((g ^ (tcol&7))*24) + hm*8];
    f32x4 ini = {fcbv, fcbv, fcbv, fcbv};
    d2[g] = __builtin_amdgcn_mfma_f32_16x16x32_bf16(a2, b2, ini, 0,0,0);
  }
  __syncthreads();

  if(tcol<12){
    float rwa[4], rba[4];
    #pragma unroll
    for(int r=0;r<4;r++){ int c=w*16+hq*4+r; rwa[r]=rw[c]; rba[r]=rb[c]; }
    #pragma unroll
    for(int g=0; g<8; g++){
      float xv=xres[g][tcol];
      #pragma unroll
      for(int r=0;r<4;r++){
        int c=w*16+hq*4+r;
        float tv = fmaxf(d2[g][r], 0.f);
        float xr = xv*rwa[r]+rba[r];
        U.XP[g][c*12+tcol] = fmaxf(xr+tv, 0.f);
      }
    }
  }
  __syncthreads();

  if(tid<192){
    int p=tid>>1, h=tid&1;
    int g=p/12, t=p-(p/12)*12;
    float s=0.f;
    for(int c=h*32;c<h*32+32;c++) s+=U.XP[g][c*12+t];
    s += __shfl_xor(s,1,64);
    float mu=s*(1.f/64.f);
    float q=0.f;
    for(int c=h*32;c<h*32+32;c++){float d=U.XP[g][c*12+t]-mu;q+=d*d;}
    q += __shfl_xor(q,1,64);
    if(h==0){ mu8[g][t]=mu; rs8[g][t]=rsqrtf(q*(1.f/64.f)+EPS); }
  }
  __syncthreads();
  for(int o=tid;o<1536;o+=256){
    int g=o/192; int q4=o-g*192;
    int c=q4/3; int tb=(q4-c*3)*4;
    float4 vv = *(const float4*)&U.XP[g][c*12+tb];
    float gl=gln[c], bl=bln[c];
    float4 ov;
    ov.x=(vv.x-mu8[g][tb+0])*rs8[g][tb+0]*gl+bl;
    ov.y=(vv.y-mu8[g][tb+1])*rs8[g][tb+1]*gl+bl;
    ov.z=(vv.z-mu8[g][tb+2])*rs8[g][tb+2]*gl+bl;
    ov.w=(vv.w-mu8[g][tb+3])*rs8[g][tb+3]*gl+bl;
    *(float4*)&out[(long)(bn0+g)*768 + c*12 + tb] = ov;
  }
}

// ---------------- launch ----------------
extern "C" void kernel_launch(void* const* d_in, const int* in_sizes, int n_in,
                              void* d_out, int out_size, void* d_ws, size_t ws_size,
                              hipStream_t stream){
  const float* x    =(const float*)d_in[0];
  const float* res  =(const float*)d_in[1];
  const float* posT =(const float*)d_in[2];
  const float* gT   =(const float*)d_in[3];
  const float* bT   =(const float*)d_in[4];
  const float* wq   =(const float*)d_in[5];
  const float* wk   =(const float*)d_in[6];
  const float* wv   =(const float*)d_in[7];
  const float* fcW  =(const float*)d_in[8];
  const float* prw  =(const float*)d_in[9];
  const float* prb  =(const float*)d_in[10];
  const float* posS =(const float*)d_in[11];
  const float* gS   =(const float*)d_in[12];
  const float* bS   =(const float*)d_in[13];
  const float* swq  =(const float*)d_in[14];
  const float* swk  =(const float*)d_in[15];
  const float* cheb =(const float*)d_in[16];
  const float* adj  =(const float*)d_in[17];
  const float* cmask=(const float*)d_in[18];
  const float* theta=(const float*)d_in[19];
  const float* g3w=(const float*)d_in[20]; const float* g3b=(const float*)d_in[21];
  const float* g5w=(const float*)d_in[22]; const float* g5b=(const float*)d_in[23];
  const float* g7w=(const float*)d_in[24]; const float* g7b=(const float*)d_in[25];
  const float* fcw=(const float*)d_in[26]; const float* fcb=(const float*)d_in[27];
  const float* rw =(const float*)d_in[28]; const float* rb =(const float*)d_in[29];
  const float* gln=(const float*)d_in[30]; const float* bln=(const float*)d_in[31];

  float* outp=(float*)d_out;
  float* scores = outp + 12582912;

  float* wsf=(float*)d_ws;
  float* TEmx = wsf;                          // 196608 f
  float* qkv  = TEmx + 196608;                // 55296 f
  float* TATpre = qkv + 55296;                // 196608 f
  unsigned short* SEb = (unsigned short*)(TATpre + 196608);      // 4194304 f
  unsigned short* SQb = (unsigned short*)((float*)SEb + 4194304); // 786432 f
  unsigned short* SKb = (unsigned short*)((float*)SQb + 786432);  // 786432 f
  unsigned* mcT = (unsigned*)((float*)SKb + 786432);              // 3145728 f
  float* rhsT  = (float*)mcT + 3145728;                           // 589824 f
  unsigned short* Apack = (unsigned short*)(rhsT + 589824);       // 122880 u16
  unsigned short* Wpack = Apack + 122880;                         // 98304 u16
  unsigned short* Wpack2 = Wpack + 98304;                         // 294912 u16
  unsigned short* TEb = Wpack2 + 294912;                          // 196608 u16
  unsigned short* fcwB = TEb + 196608;                            // 512 u16
  unsigned short* ctxb = fcwB + 512;                              // 18432 u16
  unsigned short* fcWB2 = ctxb + 18432;                           // 98304 u16
  float* muT = (float*)(fcWB2 + 98304);                           // 192 f
  float* rsT = muT + 192;                                         // 192 f

  kbp_prep<<<dim3(1069),dim3(256),0,stream>>>(adj,cmask,cheb,mcT,
                                              g3w,g5w,g7w,swq,swk,wq,wk,wv,fcw,fcW,
                                              Apack,Wpack,Wpack2,fcwB,fcWB2);
  k1_embedT<<<dim3(192),dim3(256),0,stream>>>(x,posT,gT,bT,TEmx,TEb);
  k2_qkv<<<dim3(216),dim3(256),0,stream>>>(TEb,Wpack2,qkv);
  k3_attn<<<dim3(48),dim3(256),0,stream>>>(qkv,res,scores,ctxb);
  k4a_mm<<<dim3(192),dim3(256),0,stream>>>(ctxb,fcWB2,TEmx,TATpre);
  k4b_stats<<<dim3(192),dim3(256),0,stream>>>(TATpre,muT,rsT);
  k5_semx<<<dim3(2048),dim3(256),0,stream>>>(TATpre,muT,rsT,prw,prb,posS,gS,bS,SEb);
  k6_sqk<<<dim3(1024),dim3(256),0,stream>>>(SEb,Wpack,SQb,SKb);
  k7_spatial<<<dim3(768),dim3(256),0,stream>>>(SQb,SKb,mcT,x,rhsT);
  k9_final<<<dim3(2048),dim3(256),0,stream>>>(rhsT,theta,Apack,fcwB,g3b,g5b,g7b,
                                              fcb,rw,rb,gln,bln,x,outp);
}

// Round 16
// 131.044 us; speedup vs baseline: 1.1159x; 1.0781x over previous
//
#include <hip/hip_runtime.h>
#include <hip/hip_fp16.h>

#define EPS 1e-5f

typedef float f32x4 __attribute__((ext_vector_type(4)));
typedef short bf16x8 __attribute__((ext_vector_type(8)));
typedef short bf16x4 __attribute__((ext_vector_type(4)));

__device__ __forceinline__ unsigned short f2b(float f){
  unsigned u=__float_as_uint(f);
  return (unsigned short)((u + 0x7fffu + ((u>>16)&1u))>>16);
}
__device__ __forceinline__ float b2f(unsigned short h){
  return __uint_as_float(((unsigned)h)<<16);
}

// ---------------- helpers ----------------
__device__ __forceinline__ float blockSum256(float v, float* red){
  #pragma unroll
  for(int o=32;o>0;o>>=1) v += __shfl_down(v,o,64);
  int wid = threadIdx.x>>6;
  if((threadIdx.x&63)==0) red[wid]=v;
  __syncthreads();
  if(threadIdx.x==0) red[0]=red[0]+red[1]+red[2]+red[3];
  __syncthreads();
  float r = red[0];
  __syncthreads();
  return r;
}

// ---------------- KBP1: fused prep — mcT transpose (0..767) + weight packing (768..1068) + EmbedT (1069..1260) ----
__global__ __launch_bounds__(256) void kbp1_prep(const float* __restrict__ adj, const float* __restrict__ cmask,
    const float* __restrict__ cheb, unsigned* __restrict__ mcT,
    const float* __restrict__ g3w, const float* __restrict__ g5w,
    const float* __restrict__ g7w, const float* __restrict__ swq, const float* __restrict__ swk,
    const float* __restrict__ wq, const float* __restrict__ wk, const float* __restrict__ wv,
    const float* __restrict__ fcw, const float* __restrict__ fcW,
    unsigned short* __restrict__ Apack, unsigned short* __restrict__ Wpack,
    unsigned short* __restrict__ Wpack2, unsigned short* __restrict__ fcwB,
    unsigned short* __restrict__ fcWB2,
    const float* __restrict__ x, const float* __restrict__ posT,
    const float* __restrict__ gT, const float* __restrict__ bT,
    float* __restrict__ TEmx, unsigned short* __restrict__ TEb){
  int tid=threadIdx.x;
  __shared__ union { unsigned tile[64][65]; float red[4]; } SH;
  if(blockIdx.x<768){
    int blk=blockIdx.x;                 // k*256 + tn*16 + tm
    int k=blk>>8; int rem=blk&255; int tn=rem>>4, tm=rem&15;
    const float* chk = cheb + k*1048576;
    const float* cmk = cmask + k*1048576;
    for(int i=tid;i<4096;i+=256){
      int ln=i>>6, lm=i&63;
      int n=tn*64+ln, m=tm*64+lm;
      int nm=n*1024+m;
      SH.tile[ln][lm] = (((unsigned)f2b(chk[nm]))<<16) | (unsigned)f2b(adj[nm]*cmk[nm]);
    }
    __syncthreads();
    unsigned* dst = mcT + k*1048576;
    for(int i=tid;i<4096;i+=256){
      int lm=i>>6, ln=i&63;
      dst[(tm*64+lm)*1024 + tn*64+ln] = SH.tile[ln][lm];
    }
    return;
  }
  if(blockIdx.x>=1069){
    // EmbedT body
    int bt=blockIdx.x-1069; int b=bt/12, t=bt-b*12;
    float v[4]; float s=0.f;
    #pragma unroll
    for(int i=0;i<4;i++){ int n=tid+i*256; v[i]=x[(b*1024+n)*12+t]+posT[t*1024+n]; s+=v[i]; }
    s = blockSum256(s, SH.red);
    float mu = s*(1.f/1024.f);
    float q=0.f;
    #pragma unroll
    for(int i=0;i<4;i++){ float d=v[i]-mu; q+=d*d; }
    q = blockSum256(q, SH.red);
    float rstd = rsqrtf(q*(1.f/1024.f)+EPS);
    #pragma unroll
    for(int i=0;i<4;i++){
      int n=tid+i*256;
      float val=(v[i]-mu)*rstd*gT[n]+bT[n];
      TEmx[bt*1024+n]=val;
      TEb[bt*1024+n]=f2b(val);
    }
    return;
  }
  int idx = (blockIdx.x-768)*256+tid;
  if(idx<15360){                                   // Apack (conv A-frags, bf16)
    int frag=idx>>6, lane=idx&63;
    int rt, s, kappa; const float* W;
    if(frag<48){ rt=frag/6; s=frag-rt*6; kappa=3; W=g3w; }
    else if(frag<128){ int f=frag-48; rt=f/10; s=f-rt*10; kappa=5; W=g5w; }
    else { int f=frag-128; rt=f/14; s=f-rt*14; kappa=7; W=g7w; }
    int c = rt*16 + (lane&15);
    int dt = s>>1, ic0=(s&1)*32 + (lane>>4)*8;
    #pragma unroll
    for(int j=0;j<8;j++) Apack[idx*8+j]=f2b(W[(c*64+ic0+j)*kappa + dt]);
  } else if(idx<27648){                            // Wpack (swq/swk B-frags)
    int id2=idx-15360;
    int frag=id2>>6, lane=id2&63;
    int ct=frag>>4, ks=frag&15;
    const float* W = (ct<6)? swq : swk;
    int c = ((ct<6)? ct : ct-6)*16 + (lane&15);
    int k0 = ks*32 + (lane>>4)*8;
    #pragma unroll
    for(int j=0;j<8;j++) Wpack[id2*8+j]=f2b(W[(k0+j)*96 + c]);
  } else if(idx<64512){                            // Wpack2 (wq|wk|wv B-frags)
    int id2=idx-27648;
    int frag=id2>>6, lane=id2&63;
    int ct=frag>>5, ks=frag&31;
    int cg = ct*16 + (lane&15);
    const float* W; int c;
    if(cg<96){ W=wq; c=cg; } else if(cg<192){ W=wk; c=cg-96; } else { W=wv; c=cg-192; }
    int k0 = ks*32 + (lane>>4)*8;
    #pragma unroll
    for(int j=0;j<8;j++) Wpack2[id2*8+j]=f2b(W[(k0+j)*96 + c]);
  } else if(idx<64576){                            // fcwB (bf16)
    int lane=idx-64512;
    int t=lane&15, hq=lane>>4;
    #pragma unroll
    for(int j=0;j<8;j++){
      int tau=hq*8+j;
      fcwB[lane*8+j] = (tau<24 && t<12) ? f2b(fcw[tau*12+t]) : (unsigned short)0;
    }
  } else if(idx<76864){                            // fcWB2 (fcW B-frags: 64 ct x 3 ks)
    int id3=idx-64576;
    int frag=id3>>6, lane=id3&63;
    int ct=frag/3, ks=frag-ct*3;
    int c = ct*16 + (lane&15);
    int k0 = ks*32 + (lane>>4)*8;
    #pragma unroll
    for(int j=0;j<8;j++) fcWB2[id3*8+j]=f2b(fcW[(k0+j)*1024 + c]);
  }
}

// ---------------- K2: QKV via MFMA split-K GEMM ----------------
__global__ __launch_bounds__(256) void k2_qkv(const unsigned short* __restrict__ TEb,
    const unsigned short* __restrict__ Wpack2, float* __restrict__ qkv){
  int tid=threadIdx.x; int w=tid>>6, lane=tid&63;
  const int hi=lane>>4, lo=lane&15;
  const int rt=blockIdx.x/18, ct=blockIdx.x-rt*18;
  __shared__ float red[4][16][16];
  f32x4 acc={0.f,0.f,0.f,0.f};
  #pragma unroll
  for(int s=0;s<8;s++){
    int ks=w*8+s;
    bf16x8 af = *(const bf16x8*)&TEb[(rt*16+lo)*1024 + ks*32 + hi*8];
    bf16x8 bf = *(const bf16x8*)&Wpack2[((ct*32+ks)<<9) + lane*8];
    acc = __builtin_amdgcn_mfma_f32_16x16x32_bf16(af, bf, acc, 0,0,0);
  }
  #pragma unroll
  for(int r=0;r<4;r++) red[w][hi*4+r][lo]=acc[r];
  __syncthreads();
  int r16=tid>>4, c16=tid&15;
  float s = red[0][r16][c16]+red[1][r16][c16]+red[2][r16][c16]+red[3][r16][c16];
  qkv[(rt*16+r16)*288 + ct*16 + c16] = s;
}

// ---------------- K3: temporal attn, 48 blocks (b,h) ----------------
__global__ __launch_bounds__(256) void k3_attn(const float* __restrict__ qkv, const float* __restrict__ res_att,
    float* __restrict__ scores_out, unsigned short* __restrict__ ctxb){
  int bh=blockIdx.x; int b=bh/3, h=bh-(bh/3)*3;
  int tid=threadIdx.x;
  __shared__ float sS[144];
  __shared__ float sA[144];
  if(tid<144){
    int q=tid/12;
    const float* Qr=&qkv[(b*12+q)*288 + h*32];
    const float* Kr=&qkv[(b*12+(tid-q*12))*288 + 96 + h*32];
    float acc=0.f;
    #pragma unroll
    for(int d=0;d<32;d++) acc+=Qr[d]*Kr[d];
    acc = acc*0.17677669529663687f + res_att[bh*144 + tid];
    sS[tid]=acc;
    scores_out[bh*144 + tid]=acc;
  }
  __syncthreads();
  if(tid<12){
    int k2=tid;
    float mx=-1e30f;
    for(int q=0;q<12;q++) mx=fmaxf(mx,sS[q*12+k2]);
    float sum=0.f;
    for(int q=0;q<12;q++){ float e=__expf(sS[q*12+k2]-mx); sA[q*12+k2]=e; sum+=e; }
    float inv=1.f/sum;
    for(int q=0;q<12;q++) sA[q*12+k2]*=inv;
  }
  __syncthreads();
  for(int o=tid;o<384;o+=256){
    int q=o>>5, d=o&31;
    float acc=0.f;
    #pragma unroll
    for(int k2=0;k2<12;k2++) acc += sA[q*12+k2]*qkv[(b*12+k2)*288+192+h*32+d];
    ctxb[(b*12+q)*96 + h*32 + d]=f2b(acc);
  }
}

// ---------------- K4a: TATpre = ctx@fcW + TEmx via MFMA ----------------
__global__ __launch_bounds__(256) void k4a_mm(const unsigned short* __restrict__ ctxb,
    const unsigned short* __restrict__ fcWB2, const float* __restrict__ TEmx,
    float* __restrict__ TATpre){
  int tid=threadIdx.x; int w=tid>>6, lane=tid&63;
  const int hi=lane>>4, lo=lane&15;
  const int rt=blockIdx.x>>4, cg=blockIdx.x&15;
  const int ct=cg*4+w;
  f32x4 acc={0.f,0.f,0.f,0.f};
  #pragma unroll
  for(int ks=0;ks<3;ks++){
    bf16x8 af = *(const bf16x8*)&ctxb[(rt*16+lo)*96 + ks*32 + hi*8];
    bf16x8 bf = *(const bf16x8*)&fcWB2[((ct*3+ks)<<9) + lane*8];
    acc = __builtin_amdgcn_mfma_f32_16x16x32_bf16(af, bf, acc, 0,0,0);
  }
  #pragma unroll
  for(int r=0;r<4;r++){
    int row = rt*16 + hi*4 + r;
    int coln = ct*16 + lo;
    TATpre[row*1024+coln] = acc[r] + TEmx[row*1024+coln];
  }
}

// ---------------- K4b: per-row LN stats ----------------
__global__ __launch_bounds__(256) void k4b_stats(const float* __restrict__ TATpre,
    float* __restrict__ muT, float* __restrict__ rsT){
  int bt=blockIdx.x; int tid=threadIdx.x;
  __shared__ float red[4];
  const float* row=&TATpre[bt*1024];
  float a0=row[tid], a1=row[tid+256], a2=row[tid+512], a3=row[tid+768];
  float s=a0+a1+a2+a3;
  s=blockSum256(s,red);
  float mu=s*(1.f/1024.f);
  float q=(a0-mu)*(a0-mu)+(a1-mu)*(a1-mu)+(a2-mu)*(a2-mu)+(a3-mu)*(a3-mu);
  q=blockSum256(q,red);
  if(tid==0){ muT[bt]=mu; rsT[bt]=rsqrtf(q*(1.f/1024.f)+EPS); }
}

// ---------------- K56: fused SEmx (16 rows, LDS) + SQ/SK MFMA GEMM ----------------
// Phase A: two 8-row LN batches -> SEl[16][520] bf16 (padded rows).
// Phase B: k6's MFMA with A-frags from SEl.
__global__ __launch_bounds__(256) void k56_semx_sqk(const float* __restrict__ TATpre,
    const float* __restrict__ muT, const float* __restrict__ rsT,
    const float* __restrict__ pre_w, const float* __restrict__ pre_b,
    const float* __restrict__ posS, const float* __restrict__ gS, const float* __restrict__ bS,
    const unsigned short* __restrict__ Wpack,
    unsigned short* __restrict__ SQb, unsigned short* __restrict__ SKb){
  int bn0=blockIdx.x*16; int b=bn0>>10, n0=bn0&1023; int tid=threadIdx.x;
  __shared__ unsigned short SEl[16*520];
  __shared__ float tv[12][16];
  __shared__ float ps[8][264];
  __shared__ float pq[8][264];
  __shared__ float mur[8], rsr[8];
  if(tid<192){
    int r=tid&15, t=tid>>4;
    int bt=b*12+t;
    tv[t][r]=(TATpre[bt*1024+n0+r]-muT[bt])*rsT[bt];
  }
  __syncthreads();
  const int d0=tid, d1=tid+256;
  float w0[12], w1[12];
  {
    const float4* p0=(const float4*)&pre_w[d0*12];
    float4 a=p0[0], bb=p0[1], c=p0[2];
    w0[0]=a.x;w0[1]=a.y;w0[2]=a.z;w0[3]=a.w; w0[4]=bb.x;w0[5]=bb.y;w0[6]=bb.z;w0[7]=bb.w;
    w0[8]=c.x;w0[9]=c.y;w0[10]=c.z;w0[11]=c.w;
    const float4* p1=(const float4*)&pre_w[d1*12];
    float4 d=p1[0], e=p1[1], f=p1[2];
    w1[0]=d.x;w1[1]=d.y;w1[2]=d.z;w1[3]=d.w; w1[4]=e.x;w1[5]=e.y;w1[6]=e.z;w1[7]=e.w;
    w1[8]=f.x;w1[9]=f.y;w1[10]=f.z;w1[11]=f.w;
  }
  float pb0=pre_b[d0], pb1=pre_b[d1];
  float g0=gS[d0], b0v=bS[d0], g1=gS[d1], b1v=bS[d1];
  for(int rb=0;rb<2;rb++){
    const int rbase=rb*8;
    float v0[8], v1[8];
    #pragma unroll
    for(int r=0;r<8;r++){
      int rr=rbase+r;
      float acc0=pb0 + posS[(n0+rr)*512+d0];
      float acc1=pb1 + posS[(n0+rr)*512+d1];
      #pragma unroll
      for(int t=0;t<12;t++){ float tvv=tv[t][rr]; acc0+=tvv*w0[t]; acc1+=tvv*w1[t]; }
      v0[r]=acc0; v1[r]=acc1;
      ps[r][tid]=acc0+acc1;
      pq[r][tid]=acc0*acc0+acc1*acc1;
    }
    __syncthreads();
    {
      int row=tid>>5, l32=tid&31;
      float s=0.f, q=0.f;
      #pragma unroll
      for(int j=0;j<8;j++){ s+=ps[row][l32+j*32]; q+=pq[row][l32+j*32]; }
      #pragma unroll
      for(int o=16;o>=1;o>>=1){ s+=__shfl_xor(s,o,64); q+=__shfl_xor(q,o,64); }
      if(l32==0){
        float mu=s*(1.f/512.f);
        float var=q*(1.f/512.f)-mu*mu;
        mur[row]=mu; rsr[row]=rsqrtf(var+EPS);
      }
    }
    __syncthreads();
    #pragma unroll
    for(int r=0;r<8;r++){
      float mu=mur[r], rs=rsr[r];
      SEl[(rbase+r)*520 + d0] = f2b((v0[r]-mu)*rs*g0+b0v);
      SEl[(rbase+r)*520 + d1] = f2b((v1[r]-mu)*rs*g1+b1v);
    }
    __syncthreads();
  }
  // Phase B: SQ/SK MFMA, A from SEl
  int w=tid>>6, lane=tid&63;
  const int hi=lane>>4, lo=lane&15;
  f32x4 acc[3];
  #pragma unroll
  for(int i=0;i<3;i++){ acc[i][0]=0.f; acc[i][1]=0.f; acc[i][2]=0.f; acc[i][3]=0.f; }
  const unsigned short* arow = &SEl[lo*520 + hi*8];
  #pragma unroll
  for(int ks=0;ks<16;ks++){
    bf16x8 af = *(const bf16x8*)&arow[ks*32];
    #pragma unroll
    for(int j=0;j<3;j++){
      int ct = w*3+j;
      bf16x8 bf = *(const bf16x8*)&Wpack[((ct*16+ks)<<9) + lane*8];
      acc[j] = __builtin_amdgcn_mfma_f32_16x16x32_bf16(af, bf, acc[j], 0,0,0);
    }
  }
  #pragma unroll
  for(int j=0;j<3;j++){
    int ct = w*3+j;
    int c96 = ((ct<6)? ct : ct-6)*16 + lo;
    int kq = c96>>5, d = c96&31;
    unsigned short* dst = (ct<6)? SQb : SKb;
    #pragma unroll
    for(int r=0;r<4;r++){
      int n = bn0 + hi*4 + r;
      int bb2 = n>>10, nl = n&1023;
      dst[((bb2*3+kq)*1024+nl)*32 + d] = f2b(acc[j][r]);
    }
  }
}

// ---------------- K7: whole-x LDS stage; prefetch (no setprio) ----------------
#define SCALE7 0.17677669529663687f
__global__ __launch_bounds__(256) void k7_spatial(const unsigned short* __restrict__ SQb,
    const unsigned short* __restrict__ SKb, const unsigned* __restrict__ mcT,
    const float* __restrict__ x, float* __restrict__ rhsT){
  const int blk0=blockIdx.x;
  const int blk=(blk0&7)*96 + (blk0>>3);      // XCD-chunked: 768 = 8*96, bijective
  const int mt=blk&15, bk=blk>>4;
  const int k=bk%3, b=bk/3;
  const int m0=mt*64;
  const int tid=threadIdx.x;
  const int w=tid>>6, lane=tid&63, g=lane>>4, col=lane&15;

  __shared__ unsigned short xs[16*1024];

  const float* xb = x + b*12288;
  for(int i=tid;i<2048;i+=256) ((unsigned*)xs)[12*512 + i] = 0u;
  for(int i=tid;i<12288;i+=256){
    int n=i/12, t=i-n*12;
    xs[t*1024 + (n ^ ((t&7)<<3))] = f2b(xb[i]);
  }
  __syncthreads();

  const int m_glob = m0 + w*16 + col;
  bf16x8 bfrag = *(const bf16x8*)&SKb[((bk<<10)+m_glob)*32 + g*8];

  f32x4 O = {0.f,0.f,0.f,0.f};
  float mrun=-1e30f, lrun=0.f;

  const unsigned* mrow = mcT + k*1048576 + m_glob*1024;
  const unsigned short* sqbase = &SQb[((bk<<10)+col)*32 + g*8];
  const int swz = (col&7)<<3;

  uint4 mvc[8]; bf16x8 afc[8];
  #pragma unroll
  for(int nt=0;nt<8;nt++){
    mvc[nt] = *(const uint4*)&mrow[nt*16 + g*4];
    afc[nt] = *(const bf16x8*)&sqbase[(nt*16)*32];
  }

  #pragma unroll
  for(int ch=0; ch<8; ++ch){
    const int n0 = ch<<7;
    uint4 mvn[8]; bf16x8 afn[8];
    #pragma unroll
    for(int nt=0;nt<8;nt++){
      if(ch<7){
        mvn[nt] = *(const uint4*)&mrow[n0+128 + nt*16 + g*4];
        afn[nt] = *(const bf16x8*)&sqbase[(n0+128 + nt*16)*32];
      }
    }

    f32x4 acc[8];
    #pragma unroll
    for(int nt=0;nt<8;nt++){
      f32x4 z = {0.f,0.f,0.f,0.f};
      acc[nt] = __builtin_amdgcn_mfma_f32_16x16x32_bf16(afc[nt], bfrag, z, 0,0,0);
    }
    float cmax = -1e30f;
    #pragma unroll
    for(int nt=0;nt<8;nt++){
      #pragma unroll
      for(int r=0;r<4;r++){
        unsigned mv = (r==0)?mvc[nt].x:((r==1)?mvc[nt].y:((r==2)?mvc[nt].z:mvc[nt].w));
        float s = acc[nt][r]*SCALE7 + __uint_as_float(mv<<16);
        acc[nt][r]=s;
        cmax=fmaxf(cmax,s);
      }
    }
    cmax = fmaxf(cmax, __shfl_xor(cmax,16,64));
    cmax = fmaxf(cmax, __shfl_xor(cmax,32,64));
    float mnew = fmaxf(mrun, cmax);
    float alpha = __expf(mrun - mnew);
    float lsum = 0.f;
    unsigned short pb[8][4];
    #pragma unroll
    for(int nt=0;nt<8;nt++){
      #pragma unroll
      for(int r=0;r<4;r++){
        unsigned mv = (r==0)?mvc[nt].x:((r==1)?mvc[nt].y:((r==2)?mvc[nt].z:mvc[nt].w));
        float e = __expf(acc[nt][r] - mnew);
        lsum += e;
        pb[nt][r] = f2b(e * __uint_as_float(mv & 0xffff0000u));
      }
    }
    lsum += __shfl_xor(lsum,16,64);
    lsum += __shfl_xor(lsum,32,64);
    lrun = lrun*alpha + lsum;
    mrun = mnew;
    O[0]*=alpha; O[1]*=alpha; O[2]*=alpha; O[3]*=alpha;

    #pragma unroll
    for(int c=0;c<4;c++){
      bf16x8 pf;
      #pragma unroll
      for(int j=0;j<4;j++){ pf[j]=(short)pb[2*c][j]; pf[j+4]=(short)pb[2*c+1][j]; }
      int nlo = n0 + c*32 + g*4;
      bf16x4 lo = *(const bf16x4*)&xs[col*1024 + (nlo ^ swz)];
      bf16x4 hi = *(const bf16x4*)&xs[col*1024 + ((nlo+16) ^ swz)];
      bf16x8 ax;
      #pragma unroll
      for(int j=0;j<4;j++){ ax[j]=lo[j]; ax[j+4]=hi[j]; }
      O = __builtin_amdgcn_mfma_f32_16x16x32_bf16(ax, pf, O, 0,0,0);
    }
    #pragma unroll
    for(int nt=0;nt<8;nt++){
      if(ch<7){ mvc[nt]=mvn[nt]; afc[nt]=afn[nt]; }
    }
  }
  float inv = 1.f/lrun;
  #pragma unroll
  for(int r=0;r<4;r++){
    int t = g*4+r;
    if(t<12) rhsT[((bk*12+t)<<10) + m_glob] = O[r]*inv;
  }
}

// ---------------- K9: conv MFMA (setprio) -> gated LDS -> fc MFMA -> residual+LN ----
__global__ __launch_bounds__(256) void k9_final(const float* __restrict__ rhsT, const float* __restrict__ theta,
    const unsigned short* __restrict__ Apack, const unsigned short* __restrict__ fcwB,
    const float* __restrict__ g3b, const float* __restrict__ g5b, const float* __restrict__ g7b,
    const float* __restrict__ fcb,
    const float* __restrict__ rw, const float* __restrict__ rb,
    const float* __restrict__ gln, const float* __restrict__ bln,
    const float* __restrict__ x, float* __restrict__ out){
  int bn0=blockIdx.x*8;
  int tid=threadIdx.x;
  const int b=bn0>>10, n0=bn0&1023;

  __shared__ struct { unsigned short Xl[12*8*64]; float rstage[3][12][8]; } P0;
  __shared__ union {
    unsigned short Gl[4*16*8*24];   // [wave][c_loc][g'][tau]
    float XP[8][772];
  } U;
  __shared__ float xres[8][12];
  __shared__ float mu8[8][12], rs8[8][12];

  for(int i=tid;i<288;i+=256){
    int kk=i/96; int rem=i-kk*96; int t=rem>>3; int g=rem&7;
    P0.rstage[kk][t][g]=rhsT[((b*3+kk)*12+t)*1024 + n0 + g];
  }
  for(int i=tid;i<96;i+=256){ int g=i/12, t=i-(i/12)*12; xres[g][t]=x[(bn0+g)*12+t]; }
  __syncthreads();

  {
    int g=tid>>5, icp=tid&31;
    float th0[3], th1[3];
    #pragma unroll
    for(int kk=0;kk<3;kk++){ th0[kk]=theta[kk*64+2*icp]; th1[kk]=theta[kk*64+2*icp+1]; }
    #pragma unroll
    for(int t=0;t<12;t++){
      float r0=P0.rstage[0][t][g], r1=P0.rstage[1][t][g], r2=P0.rstage[2][t][g];
      float a0=fmaxf(r0*th0[0]+r1*th0[1]+r2*th0[2],0.f);
      float a1=fmaxf(r0*th1[0]+r1*th1[1]+r2*th1[2],0.f);
      unsigned pack = (((unsigned)f2b(a1))<<16)|(unsigned)f2b(a0);
      *(unsigned*)((char*)P0.Xl + ((t*8+g)<<7) + ((icp*4) ^ (g<<4))) = pack;
    }
  }
  __syncthreads();

  const int w=tid>>6, lane=tid&63, halfk=lane>>4, colq=lane&15;
  const int gg=colq&7, tau2=colq>>3;
  const int ca = w*16 + halfk*4;
  const char* xlb = (const char*)P0.Xl;
  unsigned short* Glw = &U.Gl[w*3072];

  #define GATE_STORE(ACCA, ACCB, TB) { \
    _Pragma("unroll") \
    for(int r=0;r<4;r++){ \
      float ya=(ACCA)[r], yb=(ACCB)[r]; \
      float e2=__expf(2.f*ya), eb=__expf(yb); \
      float gval=(e2-1.f)*eb*__frcp_rn((e2+1.f)*(eb+1.f)); \
      int c_loc=halfk*4+r; \
      Glw[c_loc*192 + ((gg ^ (c_loc&7))*24) + (TB)+tau2] = f2b(gval); \
    } }

  // ---- group kappa=3 (6 K-steps, 5 col-tiles) ----
  {
    f32x4 acA[5], acB[5];
    #pragma unroll
    for(int j=0;j<5;j++)
      #pragma unroll
      for(int r=0;r<4;r++){ acA[j][r]=g3b[ca+r]; acB[j][r]=g3b[64+ca+r]; }
    const unsigned short* ap0=&Apack[((w  )*6)*512 + lane*8];
    const unsigned short* ap1=&Apack[((w+4)*6)*512 + lane*8];
    bf16x8 a0c=*(const bf16x8*)&ap0[0];
    bf16x8 a1c=*(const bf16x8*)&ap1[0];
    #pragma unroll
    for(int s=0;s<6;s++){
      bf16x8 a0n, a1n;
      if(s<5){ a0n=*(const bf16x8*)&ap0[(s+1)*512]; a1n=*(const bf16x8*)&ap1[(s+1)*512]; }
      int dt=s>>1;
      int sl = ((((s&1)*32 + halfk*8)*2) ^ (gg<<4));
      __builtin_amdgcn_s_setprio(1);
      #pragma unroll
      for(int j=0;j<5;j++){
        int t=2*j+tau2+dt;
        bf16x8 bf = *(const bf16x8*)(xlb + ((t*8+gg)<<7) + sl);
        acA[j] = __builtin_amdgcn_mfma_f32_16x16x32_bf16(a0c, bf, acA[j], 0,0,0);
        acB[j] = __builtin_amdgcn_mfma_f32_16x16x32_bf16(a1c, bf, acB[j], 0,0,0);
      }
      __builtin_amdgcn_s_setprio(0);
      if(s<5){ a0c=a0n; a1c=a1n; }
    }
    #pragma unroll
    for(int j=0;j<5;j++) GATE_STORE(acA[j], acB[j], 2*j)
  }
  // ---- group kappa=5 (10 K-steps, 4 col-tiles) ----
  {
    f32x4 acA[4], acB[4];
    #pragma unroll
    for(int j=0;j<4;j++)
      #pragma unroll
      for(int r=0;r<4;r++){ acA[j][r]=g5b[ca+r]; acB[j][r]=g5b[64+ca+r]; }
    const unsigned short* ap0=&Apack[(48 + (w  )*10)*512 + lane*8];
    const unsigned short* ap1=&Apack[(48 + (w+4)*10)*512 + lane*8];
    bf16x8 a0c=*(const bf16x8*)&ap0[0];
    bf16x8 a1c=*(const bf16x8*)&ap1[0];
    #pragma unroll
    for(int s=0;s<10;s++){
      bf16x8 a0n, a1n;
      if(s<9){ a0n=*(const bf16x8*)&ap0[(s+1)*512]; a1n=*(const bf16x8*)&ap1[(s+1)*512]; }
      int dt=s>>1;
      int sl = ((((s&1)*32 + halfk*8)*2) ^ (gg<<4));
      __builtin_amdgcn_s_setprio(1);
      #pragma unroll
      for(int j=0;j<4;j++){
        int t=2*j+tau2+dt;
        bf16x8 bf = *(const bf16x8*)(xlb + ((t*8+gg)<<7) + sl);
        acA[j] = __builtin_amdgcn_mfma_f32_16x16x32_bf16(a0c, bf, acA[j], 0,0,0);
        acB[j] = __builtin_amdgcn_mfma_f32_16x16x32_bf16(a1c, bf, acB[j], 0,0,0);
      }
      __builtin_amdgcn_s_setprio(0);
      if(s<9){ a0c=a0n; a1c=a1n; }
    }
    #pragma unroll
    for(int j=0;j<4;j++) GATE_STORE(acA[j], acB[j], 10+2*j)
  }
  // ---- group kappa=7 (14 K-steps, 3 col-tiles) ----
  {
    f32x4 acA[3], acB[3];
    #pragma unroll
    for(int j=0;j<3;j++)
      #pragma unroll
      for(int r=0;r<4;r++){ acA[j][r]=g7b[ca+r]; acB[j][r]=g7b[64+ca+r]; }
    const unsigned short* ap0=&Apack[(128 + (w  )*14)*512 + lane*8];
    const unsigned short* ap1=&Apack[(128 + (w+4)*14)*512 + lane*8];
    bf16x8 a0c=*(const bf16x8*)&ap0[0];
    bf16x8 a1c=*(const bf16x8*)&ap1[0];
    #pragma unroll
    for(int s=0;s<14;s++){
      bf16x8 a0n, a1n;
      if(s<13){ a0n=*(const bf16x8*)&ap0[(s+1)*512]; a1n=*(const bf16x8*)&ap1[(s+1)*512]; }
      int dt=s>>1;
      int sl = ((((s&1)*32 + halfk*8)*2) ^ (gg<<4));
      __builtin_amdgcn_s_setprio(1);
      #pragma unroll
      for(int j=0;j<3;j++){
        int t=2*j+tau2+dt;
        bf16x8 bf = *(const bf16x8*)(xlb + ((t*8+gg)<<7) + sl);
        acA[j] = __builtin_amdgcn_mfma_f32_16x16x32_bf16(a0c, bf, acA[j], 0,0,0);
        acB[j] = __builtin_amdgcn_mfma_f32_16x16x32_bf16(a1c, bf, acB[j], 0,0,0);
      }
      __builtin_amdgcn_s_setprio(0);
      if(s<13){ a0c=a0n; a1c=a1n; }
    }
    #pragma unroll
    for(int j=0;j<3;j++) GATE_STORE(acA[j], acB[j], 18+2*j)
  }
  #undef GATE_STORE

  // ---- fc via MFMA ----
  const int tcol = lane&15, hq = lane>>4;
  const int hm = (hq==3)? 0 : hq;
  bf16x8 b2 = *(const bf16x8*)&fcwB[lane*8];
  float fcbv = (tcol<12)? fcb[tcol] : 0.f;
  f32x4 d2[8];
  #pragma unroll
  for(int g=0; g<8; g++){
    bf16x8 a2 = *(const bf16x8*)&Glw[tcol*192 + ((g ^ (tcol&7))*24) + hm*8];
    f32x4 ini = {fcbv, fcbv, fcbv, fcbv};
    d2[g] = __builtin_amdgcn_mfma_f32_16x16x32_bf16(a2, b2, ini, 0,0,0);
  }
  __syncthreads();

  if(tcol<12){
    float rwa[4], rba[4];
    #pragma unroll
    for(int r=0;r<4;r++){ int c=w*16+hq*4+r; rwa[r]=rw[c]; rba[r]=rb[c]; }
    #pragma unroll
    for(int g=0; g<8; g++){
      float xv=xres[g][tcol];
      #pragma unroll
      for(int r=0;r<4;r++){
        int c=w*16+hq*4+r;
        float tv = fmaxf(d2[g][r], 0.f);
        float xr = xv*rwa[r]+rba[r];
        U.XP[g][c*12+tcol] = fmaxf(xr+tv, 0.f);
      }
    }
  }
  __syncthreads();

  if(tid<192){
    int p=tid>>1, h=tid&1;
    int g=p/12, t=p-(p/12)*12;
    float s=0.f;
    for(int c=h*32;c<h*32+32;c++) s+=U.XP[g][c*12+t];
    s += __shfl_xor(s,1,64);
    float mu=s*(1.f/64.f);
    float q=0.f;
    for(int c=h*32;c<h*32+32;c++){float d=U.XP[g][c*12+t]-mu;q+=d*d;}
    q += __shfl_xor(q,1,64);
    if(h==0){ mu8[g][t]=mu; rs8[g][t]=rsqrtf(q*(1.f/64.f)+EPS); }
  }
  __syncthreads();
  for(int o=tid;o<1536;o+=256){
    int g=o/192; int q4=o-g*192;
    int c=q4/3; int tb=(q4-c*3)*4;
    float4 vv = *(const float4*)&U.XP[g][c*12+tb];
    float gl=gln[c], bl=bln[c];
    float4 ov;
    ov.x=(vv.x-mu8[g][tb+0])*rs8[g][tb+0]*gl+bl;
    ov.y=(vv.y-mu8[g][tb+1])*rs8[g][tb+1]*gl+bl;
    ov.z=(vv.z-mu8[g][tb+2])*rs8[g][tb+2]*gl+bl;
    ov.w=(vv.w-mu8[g][tb+3])*rs8[g][tb+3]*gl+bl;
    *(float4*)&out[(long)(bn0+g)*768 + c*12 + tb] = ov;
  }
}

// ---------------- launch ----------------
extern "C" void kernel_launch(void* const* d_in, const int* in_sizes, int n_in,
                              void* d_out, int out_size, void* d_ws, size_t ws_size,
                              hipStream_t stream){
  const float* x    =(const float*)d_in[0];
  const float* res  =(const float*)d_in[1];
  const float* posT =(const float*)d_in[2];
  const float* gT   =(const float*)d_in[3];
  const float* bT   =(const float*)d_in[4];
  const float* wq   =(const float*)d_in[5];
  const float* wk   =(const float*)d_in[6];
  const float* wv   =(const float*)d_in[7];
  const float* fcW  =(const float*)d_in[8];
  const float* prw  =(const float*)d_in[9];
  const float* prb  =(const float*)d_in[10];
  const float* posS =(const float*)d_in[11];
  const float* gS   =(const float*)d_in[12];
  const float* bS   =(const float*)d_in[13];
  const float* swq  =(const float*)d_in[14];
  const float* swk  =(const float*)d_in[15];
  const float* cheb =(const float*)d_in[16];
  const float* adj  =(const float*)d_in[17];
  const float* cmask=(const float*)d_in[18];
  const float* theta=(const float*)d_in[19];
  const float* g3w=(const float*)d_in[20]; const float* g3b=(const float*)d_in[21];
  const float* g5w=(const float*)d_in[22]; const float* g5b=(const float*)d_in[23];
  const float* g7w=(const float*)d_in[24]; const float* g7b=(const float*)d_in[25];
  const float* fcw=(const float*)d_in[26]; const float* fcb=(const float*)d_in[27];
  const float* rw =(const float*)d_in[28]; const float* rb =(const float*)d_in[29];
  const float* gln=(const float*)d_in[30]; const float* bln=(const float*)d_in[31];

  float* outp=(float*)d_out;
  float* scores = outp + 12582912;

  float* wsf=(float*)d_ws;
  float* TEmx = wsf;                          // 196608 f
  float* qkv  = TEmx + 196608;                // 55296 f
  float* TATpre = qkv + 55296;                // 196608 f
  unsigned short* SEb = (unsigned short*)(TATpre + 196608);      // (unused, kept for layout)
  unsigned short* SQb = (unsigned short*)((float*)SEb + 4194304); // 786432 f
  unsigned short* SKb = (unsigned short*)((float*)SQb + 786432);  // 786432 f
  unsigned* mcT = (unsigned*)((float*)SKb + 786432);              // 3145728 f
  float* rhsT  = (float*)mcT + 3145728;                           // 589824 f
  unsigned short* Apack = (unsigned short*)(rhsT + 589824);       // 122880 u16
  unsigned short* Wpack = Apack + 122880;                         // 98304 u16
  unsigned short* Wpack2 = Wpack + 98304;                         // 294912 u16
  unsigned short* TEb = Wpack2 + 294912;                          // 196608 u16
  unsigned short* fcwB = TEb + 196608;                            // 512 u16
  unsigned short* ctxb = fcwB + 512;                              // 18432 u16
  unsigned short* fcWB2 = ctxb + 18432;                           // 98304 u16
  float* muT = (float*)(fcWB2 + 98304);                           // 192 f
  float* rsT = muT + 192;                                         // 192 f

  kbp1_prep<<<dim3(1261),dim3(256),0,stream>>>(adj,cmask,cheb,mcT,
                                               g3w,g5w,g7w,swq,swk,wq,wk,wv,fcw,fcW,
                                               Apack,Wpack,Wpack2,fcwB,fcWB2,
                                               x,posT,gT,bT,TEmx,TEb);
  k2_qkv<<<dim3(216),dim3(256),0,stream>>>(TEb,Wpack2,qkv);
  k3_attn<<<dim3(48),dim3(256),0,stream>>>(qkv,res,scores,ctxb);
  k4a_mm<<<dim3(192),dim3(256),0,stream>>>(ctxb,fcWB2,TEmx,TATpre);
  k4b_stats<<<dim3(192),dim3(256),0,stream>>>(TATpre,muT,rsT);
  k56_semx_sqk<<<dim3(1024),dim3(256),0,stream>>>(TATpre,muT,rsT,prw,prb,posS,gS,bS,
                                                  Wpack,SQb,SKb);
  k7_spatial<<<dim3(768),dim3(256),0,stream>>>(SQb,SKb,mcT,x,rhsT);
  k9_final<<<dim3(2048),dim3(256),0,stream>>>(rhsT,theta,Apack,fcwB,g3b,g5b,g7b,
                                              fcb,rw,rb,gln,bln,x,outp);
}

// Round 17
// 130.711 us; speedup vs baseline: 1.1187x; 1.0025x over previous
//
#include <hip/hip_runtime.h>
#include <hip/hip_fp16.h>

#define EPS 1e-5f

typedef float f32x4 __attribute__((ext_vector_type(4)));
typedef short bf16x8 __attribute__((ext_vector_type(8)));
typedef short bf16x4 __attribute__((ext_vector_type(4)));

__device__ __forceinline__ unsigned short f2b(float f){
  unsigned u=__float_as_uint(f);
  return (unsigned short)((u + 0x7fffu + ((u>>16)&1u))>>16);
}
__device__ __forceinline__ float b2f(unsigned short h){
  return __uint_as_float(((unsigned)h)<<16);
}

// ---------------- helpers ----------------
__device__ __forceinline__ float blockSum256(float v, float* red){
  #pragma unroll
  for(int o=32;o>0;o>>=1) v += __shfl_down(v,o,64);
  int wid = threadIdx.x>>6;
  if((threadIdx.x&63)==0) red[wid]=v;
  __syncthreads();
  if(threadIdx.x==0) red[0]=red[0]+red[1]+red[2]+red[3];
  __syncthreads();
  float r = red[0];
  __syncthreads();
  return r;
}

// ---------------- KBP1: weight packing (blocks 0..300) + EmbedT (301..492) ----------------
__global__ __launch_bounds__(256) void kbp1_prep(
    const float* __restrict__ g3w, const float* __restrict__ g5w,
    const float* __restrict__ g7w, const float* __restrict__ swq, const float* __restrict__ swk,
    const float* __restrict__ wq, const float* __restrict__ wk, const float* __restrict__ wv,
    const float* __restrict__ fcw, const float* __restrict__ fcW,
    unsigned short* __restrict__ Apack, unsigned short* __restrict__ Wpack,
    unsigned short* __restrict__ Wpack2, unsigned short* __restrict__ fcwB,
    unsigned short* __restrict__ fcWB2,
    const float* __restrict__ x, const float* __restrict__ posT,
    const float* __restrict__ gT, const float* __restrict__ bT,
    float* __restrict__ TEmx, unsigned short* __restrict__ TEb){
  int tid=threadIdx.x;
  __shared__ float red[4];
  if(blockIdx.x>=301){
    // EmbedT body
    int bt=blockIdx.x-301; int b=bt/12, t=bt-b*12;
    float v[4]; float s=0.f;
    #pragma unroll
    for(int i=0;i<4;i++){ int n=tid+i*256; v[i]=x[(b*1024+n)*12+t]+posT[t*1024+n]; s+=v[i]; }
    s = blockSum256(s, red);
    float mu = s*(1.f/1024.f);
    float q=0.f;
    #pragma unroll
    for(int i=0;i<4;i++){ float d=v[i]-mu; q+=d*d; }
    q = blockSum256(q, red);
    float rstd = rsqrtf(q*(1.f/1024.f)+EPS);
    #pragma unroll
    for(int i=0;i<4;i++){
      int n=tid+i*256;
      float val=(v[i]-mu)*rstd*gT[n]+bT[n];
      TEmx[bt*1024+n]=val;
      TEb[bt*1024+n]=f2b(val);
    }
    return;
  }
  int idx = blockIdx.x*256+tid;
  if(idx<15360){                                   // Apack (conv A-frags, bf16)
    int frag=idx>>6, lane=idx&63;
    int rt, s, kappa; const float* W;
    if(frag<48){ rt=frag/6; s=frag-rt*6; kappa=3; W=g3w; }
    else if(frag<128){ int f=frag-48; rt=f/10; s=f-rt*10; kappa=5; W=g5w; }
    else { int f=frag-128; rt=f/14; s=f-rt*14; kappa=7; W=g7w; }
    int c = rt*16 + (lane&15);
    int dt = s>>1, ic0=(s&1)*32 + (lane>>4)*8;
    #pragma unroll
    for(int j=0;j<8;j++) Apack[idx*8+j]=f2b(W[(c*64+ic0+j)*kappa + dt]);
  } else if(idx<27648){                            // Wpack (swq/swk B-frags)
    int id2=idx-15360;
    int frag=id2>>6, lane=id2&63;
    int ct=frag>>4, ks=frag&15;
    const float* W = (ct<6)? swq : swk;
    int c = ((ct<6)? ct : ct-6)*16 + (lane&15);
    int k0 = ks*32 + (lane>>4)*8;
    #pragma unroll
    for(int j=0;j<8;j++) Wpack[id2*8+j]=f2b(W[(k0+j)*96 + c]);
  } else if(idx<64512){                            // Wpack2 (wq|wk|wv B-frags)
    int id2=idx-27648;
    int frag=id2>>6, lane=id2&63;
    int ct=frag>>5, ks=frag&31;
    int cg = ct*16 + (lane&15);
    const float* W; int c;
    if(cg<96){ W=wq; c=cg; } else if(cg<192){ W=wk; c=cg-96; } else { W=wv; c=cg-192; }
    int k0 = ks*32 + (lane>>4)*8;
    #pragma unroll
    for(int j=0;j<8;j++) Wpack2[id2*8+j]=f2b(W[(k0+j)*96 + c]);
  } else if(idx<64576){                            // fcwB (bf16)
    int lane=idx-64512;
    int t=lane&15, hq=lane>>4;
    #pragma unroll
    for(int j=0;j<8;j++){
      int tau=hq*8+j;
      fcwB[lane*8+j] = (tau<24 && t<12) ? f2b(fcw[tau*12+t]) : (unsigned short)0;
    }
  } else if(idx<76864){                            // fcWB2 (fcW B-frags: 64 ct x 3 ks)
    int id3=idx-64576;
    int frag=id3>>6, lane=id3&63;
    int ct=frag/3, ks=frag-ct*3;
    int c = ct*16 + (lane&15);
    int k0 = ks*32 + (lane>>4)*8;
    #pragma unroll
    for(int j=0;j<8;j++) fcWB2[id3*8+j]=f2b(fcW[(k0+j)*1024 + c]);
  }
}

// ---------------- K2: QKV MFMA tiles (blocks 0..215) + mcT transpose (216..983) ----------------
__global__ __launch_bounds__(256) void k2_qkv(const unsigned short* __restrict__ TEb,
    const unsigned short* __restrict__ Wpack2, float* __restrict__ qkv,
    const float* __restrict__ adj, const float* __restrict__ cmask,
    const float* __restrict__ cheb, unsigned* __restrict__ mcT){
  int tid=threadIdx.x;
  __shared__ union { float red[4][16][16]; unsigned tile[64][65]; } SH;
  if(blockIdx.x>=216){
    int blk=blockIdx.x-216;                 // k*256 + tn*16 + tm
    int k=blk>>8; int rem=blk&255; int tn=rem>>4, tm=rem&15;
    const float* chk = cheb + k*1048576;
    const float* cmk = cmask + k*1048576;
    for(int i=tid;i<4096;i+=256){
      int ln=i>>6, lm=i&63;
      int n=tn*64+ln, m=tm*64+lm;
      int nm=n*1024+m;
      SH.tile[ln][lm] = (((unsigned)f2b(chk[nm]))<<16) | (unsigned)f2b(adj[nm]*cmk[nm]);
    }
    __syncthreads();
    unsigned* dst = mcT + k*1048576;
    for(int i=tid;i<4096;i+=256){
      int lm=i>>6, ln=i&63;
      dst[(tm*64+lm)*1024 + tn*64+ln] = SH.tile[ln][lm];
    }
    return;
  }
  int w=tid>>6, lane=tid&63;
  const int hi=lane>>4, lo=lane&15;
  const int rt=blockIdx.x/18, ct=blockIdx.x-rt*18;
  f32x4 acc={0.f,0.f,0.f,0.f};
  #pragma unroll
  for(int s=0;s<8;s++){
    int ks=w*8+s;
    bf16x8 af = *(const bf16x8*)&TEb[(rt*16+lo)*1024 + ks*32 + hi*8];
    bf16x8 bf = *(const bf16x8*)&Wpack2[((ct*32+ks)<<9) + lane*8];
    acc = __builtin_amdgcn_mfma_f32_16x16x32_bf16(af, bf, acc, 0,0,0);
  }
  #pragma unroll
  for(int r=0;r<4;r++) SH.red[w][hi*4+r][lo]=acc[r];
  __syncthreads();
  int r16=tid>>4, c16=tid&15;
  float s = SH.red[0][r16][c16]+SH.red[1][r16][c16]+SH.red[2][r16][c16]+SH.red[3][r16][c16];
  qkv[(rt*16+r16)*288 + ct*16 + c16] = s;
}

// ---------------- K3: temporal attn, 48 blocks (b,h) ----------------
__global__ __launch_bounds__(256) void k3_attn(const float* __restrict__ qkv, const float* __restrict__ res_att,
    float* __restrict__ scores_out, unsigned short* __restrict__ ctxb){
  int bh=blockIdx.x; int b=bh/3, h=bh-(bh/3)*3;
  int tid=threadIdx.x;
  __shared__ float sS[144];
  __shared__ float sA[144];
  if(tid<144){
    int q=tid/12;
    const float* Qr=&qkv[(b*12+q)*288 + h*32];
    const float* Kr=&qkv[(b*12+(tid-q*12))*288 + 96 + h*32];
    float acc=0.f;
    #pragma unroll
    for(int d=0;d<32;d++) acc+=Qr[d]*Kr[d];
    acc = acc*0.17677669529663687f + res_att[bh*144 + tid];
    sS[tid]=acc;
    scores_out[bh*144 + tid]=acc;
  }
  __syncthreads();
  if(tid<12){
    int k2=tid;
    float mx=-1e30f;
    for(int q=0;q<12;q++) mx=fmaxf(mx,sS[q*12+k2]);
    float sum=0.f;
    for(int q=0;q<12;q++){ float e=__expf(sS[q*12+k2]-mx); sA[q*12+k2]=e; sum+=e; }
    float inv=1.f/sum;
    for(int q=0;q<12;q++) sA[q*12+k2]*=inv;
  }
  __syncthreads();
  for(int o=tid;o<384;o+=256){
    int q=o>>5, d=o&31;
    float acc=0.f;
    #pragma unroll
    for(int k2=0;k2<12;k2++) acc += sA[q*12+k2]*qkv[(b*12+k2)*288+192+h*32+d];
    ctxb[(b*12+q)*96 + h*32 + d]=f2b(acc);
  }
}

// ---------------- K4a: TATpre = ctx@fcW + TEmx via MFMA ----------------
__global__ __launch_bounds__(256) void k4a_mm(const unsigned short* __restrict__ ctxb,
    const unsigned short* __restrict__ fcWB2, const float* __restrict__ TEmx,
    float* __restrict__ TATpre){
  int tid=threadIdx.x; int w=tid>>6, lane=tid&63;
  const int hi=lane>>4, lo=lane&15;
  const int rt=blockIdx.x>>4, cg=blockIdx.x&15;
  const int ct=cg*4+w;
  f32x4 acc={0.f,0.f,0.f,0.f};
  #pragma unroll
  for(int ks=0;ks<3;ks++){
    bf16x8 af = *(const bf16x8*)&ctxb[(rt*16+lo)*96 + ks*32 + hi*8];
    bf16x8 bf = *(const bf16x8*)&fcWB2[((ct*3+ks)<<9) + lane*8];
    acc = __builtin_amdgcn_mfma_f32_16x16x32_bf16(af, bf, acc, 0,0,0);
  }
  #pragma unroll
  for(int r=0;r<4;r++){
    int row = rt*16 + hi*4 + r;
    int coln = ct*16 + lo;
    TATpre[row*1024+coln] = acc[r] + TEmx[row*1024+coln];
  }
}

// ---------------- K4b: per-row LN stats ----------------
__global__ __launch_bounds__(256) void k4b_stats(const float* __restrict__ TATpre,
    float* __restrict__ muT, float* __restrict__ rsT){
  int bt=blockIdx.x; int tid=threadIdx.x;
  __shared__ float red[4];
  const float* row=&TATpre[bt*1024];
  float a0=row[tid], a1=row[tid+256], a2=row[tid+512], a3=row[tid+768];
  float s=a0+a1+a2+a3;
  s=blockSum256(s,red);
  float mu=s*(1.f/1024.f);
  float q=(a0-mu)*(a0-mu)+(a1-mu)*(a1-mu)+(a2-mu)*(a2-mu)+(a3-mu)*(a3-mu);
  q=blockSum256(q,red);
  if(tid==0){ muT[bt]=mu; rsT[bt]=rsqrtf(q*(1.f/1024.f)+EPS); }
}

// ---------------- K56: fused SEmx (16 rows, LDS) + SQ/SK MFMA GEMM ----------------
__global__ __launch_bounds__(256) void k56_semx_sqk(const float* __restrict__ TATpre,
    const float* __restrict__ muT, const float* __restrict__ rsT,
    const float* __restrict__ pre_w, const float* __restrict__ pre_b,
    const float* __restrict__ posS, const float* __restrict__ gS, const float* __restrict__ bS,
    const unsigned short* __restrict__ Wpack,
    unsigned short* __restrict__ SQb, unsigned short* __restrict__ SKb){
  int bn0=blockIdx.x*16; int b=bn0>>10, n0=bn0&1023; int tid=threadIdx.x;
  __shared__ unsigned short SEl[16*520];
  __shared__ float tv[12][16];
  __shared__ float ps[8][264];
  __shared__ float pq[8][264];
  __shared__ float mur[8], rsr[8];
  if(tid<192){
    int r=tid&15, t=tid>>4;
    int bt=b*12+t;
    tv[t][r]=(TATpre[bt*1024+n0+r]-muT[bt])*rsT[bt];
  }
  __syncthreads();
  const int d0=tid, d1=tid+256;
  float w0[12], w1[12];
  {
    const float4* p0=(const float4*)&pre_w[d0*12];
    float4 a=p0[0], bb=p0[1], c=p0[2];
    w0[0]=a.x;w0[1]=a.y;w0[2]=a.z;w0[3]=a.w; w0[4]=bb.x;w0[5]=bb.y;w0[6]=bb.z;w0[7]=bb.w;
    w0[8]=c.x;w0[9]=c.y;w0[10]=c.z;w0[11]=c.w;
    const float4* p1=(const float4*)&pre_w[d1*12];
    float4 d=p1[0], e=p1[1], f=p1[2];
    w1[0]=d.x;w1[1]=d.y;w1[2]=d.z;w1[3]=d.w; w1[4]=e.x;w1[5]=e.y;w1[6]=e.z;w1[7]=e.w;
    w1[8]=f.x;w1[9]=f.y;w1[10]=f.z;w1[11]=f.w;
  }
  float pb0=pre_b[d0], pb1=pre_b[d1];
  float g0=gS[d0], b0v=bS[d0], g1=gS[d1], b1v=bS[d1];
  for(int rb=0;rb<2;rb++){
    const int rbase=rb*8;
    float v0[8], v1[8];
    #pragma unroll
    for(int r=0;r<8;r++){
      int rr=rbase+r;
      float acc0=pb0 + posS[(n0+rr)*512+d0];
      float acc1=pb1 + posS[(n0+rr)*512+d1];
      #pragma unroll
      for(int t=0;t<12;t++){ float tvv=tv[t][rr]; acc0+=tvv*w0[t]; acc1+=tvv*w1[t]; }
      v0[r]=acc0; v1[r]=acc1;
      ps[r][tid]=acc0+acc1;
      pq[r][tid]=acc0*acc0+acc1*acc1;
    }
    __syncthreads();
    {
      int row=tid>>5, l32=tid&31;
      float s=0.f, q=0.f;
      #pragma unroll
      for(int j=0;j<8;j++){ s+=ps[row][l32+j*32]; q+=pq[row][l32+j*32]; }
      #pragma unroll
      for(int o=16;o>=1;o>>=1){ s+=__shfl_xor(s,o,64); q+=__shfl_xor(q,o,64); }
      if(l32==0){
        float mu=s*(1.f/512.f);
        float var=q*(1.f/512.f)-mu*mu;
        mur[row]=mu; rsr[row]=rsqrtf(var+EPS);
      }
    }
    __syncthreads();
    #pragma unroll
    for(int r=0;r<8;r++){
      float mu=mur[r], rs=rsr[r];
      SEl[(rbase+r)*520 + d0] = f2b((v0[r]-mu)*rs*g0+b0v);
      SEl[(rbase+r)*520 + d1] = f2b((v1[r]-mu)*rs*g1+b1v);
    }
    __syncthreads();
  }
  // Phase B: SQ/SK MFMA, A from SEl
  int w=tid>>6, lane=tid&63;
  const int hi=lane>>4, lo=lane&15;
  f32x4 acc[3];
  #pragma unroll
  for(int i=0;i<3;i++){ acc[i][0]=0.f; acc[i][1]=0.f; acc[i][2]=0.f; acc[i][3]=0.f; }
  const unsigned short* arow = &SEl[lo*520 + hi*8];
  #pragma unroll
  for(int ks=0;ks<16;ks++){
    bf16x8 af = *(const bf16x8*)&arow[ks*32];
    #pragma unroll
    for(int j=0;j<3;j++){
      int ct = w*3+j;
      bf16x8 bf = *(const bf16x8*)&Wpack[((ct*16+ks)<<9) + lane*8];
      acc[j] = __builtin_amdgcn_mfma_f32_16x16x32_bf16(af, bf, acc[j], 0,0,0);
    }
  }
  #pragma unroll
  for(int j=0;j<3;j++){
    int ct = w*3+j;
    int c96 = ((ct<6)? ct : ct-6)*16 + lo;
    int kq = c96>>5, d = c96&31;
    unsigned short* dst = (ct<6)? SQb : SKb;
    #pragma unroll
    for(int r=0;r<4;r++){
      int n = bn0 + hi*4 + r;
      int bb2 = n>>10, nl = n&1023;
      dst[((bb2*3+kq)*1024+nl)*32 + d] = f2b(acc[j][r]);
    }
  }
}

// ---------------- K7: whole-x LDS stage; prefetch (no setprio) ----------------
#define SCALE7 0.17677669529663687f
__global__ __launch_bounds__(256) void k7_spatial(const unsigned short* __restrict__ SQb,
    const unsigned short* __restrict__ SKb, const unsigned* __restrict__ mcT,
    const float* __restrict__ x, float* __restrict__ rhsT){
  const int blk0=blockIdx.x;
  const int blk=(blk0&7)*96 + (blk0>>3);      // XCD-chunked: 768 = 8*96, bijective
  const int mt=blk&15, bk=blk>>4;
  const int k=bk%3, b=bk/3;
  const int m0=mt*64;
  const int tid=threadIdx.x;
  const int w=tid>>6, lane=tid&63, g=lane>>4, col=lane&15;

  __shared__ unsigned short xs[16*1024];

  const float* xb = x + b*12288;
  for(int i=tid;i<2048;i+=256) ((unsigned*)xs)[12*512 + i] = 0u;
  for(int i=tid;i<12288;i+=256){
    int n=i/12, t=i-n*12;
    xs[t*1024 + (n ^ ((t&7)<<3))] = f2b(xb[i]);
  }
  __syncthreads();

  const int m_glob = m0 + w*16 + col;
  bf16x8 bfrag = *(const bf16x8*)&SKb[((bk<<10)+m_glob)*32 + g*8];

  f32x4 O = {0.f,0.f,0.f,0.f};
  float mrun=-1e30f, lrun=0.f;

  const unsigned* mrow = mcT + k*1048576 + m_glob*1024;
  const unsigned short* sqbase = &SQb[((bk<<10)+col)*32 + g*8];
  const int swz = (col&7)<<3;

  uint4 mvc[8]; bf16x8 afc[8];
  #pragma unroll
  for(int nt=0;nt<8;nt++){
    mvc[nt] = *(const uint4*)&mrow[nt*16 + g*4];
    afc[nt] = *(const bf16x8*)&sqbase[(nt*16)*32];
  }

  #pragma unroll
  for(int ch=0; ch<8; ++ch){
    const int n0 = ch<<7;
    uint4 mvn[8]; bf16x8 afn[8];
    #pragma unroll
    for(int nt=0;nt<8;nt++){
      if(ch<7){
        mvn[nt] = *(const uint4*)&mrow[n0+128 + nt*16 + g*4];
        afn[nt] = *(const bf16x8*)&sqbase[(n0+128 + nt*16)*32];
      }
    }

    f32x4 acc[8];
    #pragma unroll
    for(int nt=0;nt<8;nt++){
      f32x4 z = {0.f,0.f,0.f,0.f};
      acc[nt] = __builtin_amdgcn_mfma_f32_16x16x32_bf16(afc[nt], bfrag, z, 0,0,0);
    }
    float cmax = -1e30f;
    #pragma unroll
    for(int nt=0;nt<8;nt++){
      #pragma unroll
      for(int r=0;r<4;r++){
        unsigned mv = (r==0)?mvc[nt].x:((r==1)?mvc[nt].y:((r==2)?mvc[nt].z:mvc[nt].w));
        float s = acc[nt][r]*SCALE7 + __uint_as_float(mv<<16);
        acc[nt][r]=s;
        cmax=fmaxf(cmax,s);
      }
    }
    cmax = fmaxf(cmax, __shfl_xor(cmax,16,64));
    cmax = fmaxf(cmax, __shfl_xor(cmax,32,64));
    float mnew = fmaxf(mrun, cmax);
    float alpha = __expf(mrun - mnew);
    float lsum = 0.f;
    unsigned short pb[8][4];
    #pragma unroll
    for(int nt=0;nt<8;nt++){
      #pragma unroll
      for(int r=0;r<4;r++){
        unsigned mv = (r==0)?mvc[nt].x:((r==1)?mvc[nt].y:((r==2)?mvc[nt].z:mvc[nt].w));
        float e = __expf(acc[nt][r] - mnew);
        lsum += e;
        pb[nt][r] = f2b(e * __uint_as_float(mv & 0xffff0000u));
      }
    }
    lsum += __shfl_xor(lsum,16,64);
    lsum += __shfl_xor(lsum,32,64);
    lrun = lrun*alpha + lsum;
    mrun = mnew;
    O[0]*=alpha; O[1]*=alpha; O[2]*=alpha; O[3]*=alpha;

    #pragma unroll
    for(int c=0;c<4;c++){
      bf16x8 pf;
      #pragma unroll
      for(int j=0;j<4;j++){ pf[j]=(short)pb[2*c][j]; pf[j+4]=(short)pb[2*c+1][j]; }
      int nlo = n0 + c*32 + g*4;
      bf16x4 lo = *(const bf16x4*)&xs[col*1024 + (nlo ^ swz)];
      bf16x4 hi = *(const bf16x4*)&xs[col*1024 + ((nlo+16) ^ swz)];
      bf16x8 ax;
      #pragma unroll
      for(int j=0;j<4;j++){ ax[j]=lo[j]; ax[j+4]=hi[j]; }
      O = __builtin_amdgcn_mfma_f32_16x16x32_bf16(ax, pf, O, 0,0,0);
    }
    #pragma unroll
    for(int nt=0;nt<8;nt++){
      if(ch<7){ mvc[nt]=mvn[nt]; afc[nt]=afn[nt]; }
    }
  }
  float inv = 1.f/lrun;
  #pragma unroll
  for(int r=0;r<4;r++){
    int t = g*4+r;
    if(t<12) rhsT[((bk*12+t)<<10) + m_glob] = O[r]*inv;
  }
}

// ---------------- K9: conv MFMA (setprio) -> gated LDS -> fc MFMA -> residual+LN ----
__global__ __launch_bounds__(256) void k9_final(const float* __restrict__ rhsT, const float* __restrict__ theta,
    const unsigned short* __restrict__ Apack, const unsigned short* __restrict__ fcwB,
    const float* __restrict__ g3b, const float* __restrict__ g5b, const float* __restrict__ g7b,
    const float* __restrict__ fcb,
    const float* __restrict__ rw, const float* __restrict__ rb,
    const float* __restrict__ gln, const float* __restrict__ bln,
    const float* __restrict__ x, float* __restrict__ out){
  int bn0=blockIdx.x*8;
  int tid=threadIdx.x;
  const int b=bn0>>10, n0=bn0&1023;

  __shared__ struct { unsigned short Xl[12*8*64]; float rstage[3][12][8]; } P0;
  __shared__ union {
    unsigned short Gl[4*16*8*24];   // [wave][c_loc][g'][tau]
    float XP[8][772];
  } U;
  __shared__ float xres[8][12];
  __shared__ float mu8[8][12], rs8[8][12];

  for(int i=tid;i<288;i+=256){
    int kk=i/96; int rem=i-kk*96; int t=rem>>3; int g=rem&7;
    P0.rstage[kk][t][g]=rhsT[((b*3+kk)*12+t)*1024 + n0 + g];
  }
  for(int i=tid;i<96;i+=256){ int g=i/12, t=i-(i/12)*12; xres[g][t]=x[(bn0+g)*12+t]; }
  __syncthreads();

  {
    int g=tid>>5, icp=tid&31;
    float th0[3], th1[3];
    #pragma unroll
    for(int kk=0;kk<3;kk++){ th0[kk]=theta[kk*64+2*icp]; th1[kk]=theta[kk*64+2*icp+1]; }
    #pragma unroll
    for(int t=0;t<12;t++){
      float r0=P0.rstage[0][t][g], r1=P0.rstage[1][t][g], r2=P0.rstage[2][t][g];
      float a0=fmaxf(r0*th0[0]+r1*th0[1]+r2*th0[2],0.f);
      float a1=fmaxf(r0*th1[0]+r1*th1[1]+r2*th1[2],0.f);
      unsigned pack = (((unsigned)f2b(a1))<<16)|(unsigned)f2b(a0);
      *(unsigned*)((char*)P0.Xl + ((t*8+g)<<7) + ((icp*4) ^ (g<<4))) = pack;
    }
  }
  __syncthreads();

  const int w=tid>>6, lane=tid&63, halfk=lane>>4, colq=lane&15;
  const int gg=colq&7, tau2=colq>>3;
  const int ca = w*16 + halfk*4;
  const char* xlb = (const char*)P0.Xl;
  unsigned short* Glw = &U.Gl[w*3072];

  #define GATE_STORE(ACCA, ACCB, TB) { \
    _Pragma("unroll") \
    for(int r=0;r<4;r++){ \
      float ya=(ACCA)[r], yb=(ACCB)[r]; \
      float e2=__expf(2.f*ya), eb=__expf(yb); \
      float gval=(e2-1.f)*eb*__frcp_rn((e2+1.f)*(eb+1.f)); \
      int c_loc=halfk*4+r; \
      Glw[c_loc*192 + ((gg ^ (c_loc&7))*24) + (TB)+tau2] = f2b(gval); \
    } }

  // ---- group kappa=3 (6 K-steps, 5 col-tiles) ----
  {
    f32x4 acA[5], acB[5];
    #pragma unroll
    for(int j=0;j<5;j++)
      #pragma unroll
      for(int r=0;r<4;r++){ acA[j][r]=g3b[ca+r]; acB[j][r]=g3b[64+ca+r]; }
    const unsigned short* ap0=&Apack[((w  )*6)*512 + lane*8];
    const unsigned short* ap1=&Apack[((w+4)*6)*512 + lane*8];
    bf16x8 a0c=*(const bf16x8*)&ap0[0];
    bf16x8 a1c=*(const bf16x8*)&ap1[0];
    #pragma unroll
    for(int s=0;s<6;s++){
      bf16x8 a0n, a1n;
      if(s<5){ a0n=*(const bf16x8*)&ap0[(s+1)*512]; a1n=*(const bf16x8*)&ap1[(s+1)*512]; }
      int dt=s>>1;
      int sl = ((((s&1)*32 + halfk*8)*2) ^ (gg<<4));
      __builtin_amdgcn_s_setprio(1);
      #pragma unroll
      for(int j=0;j<5;j++){
        int t=2*j+tau2+dt;
        bf16x8 bf = *(const bf16x8*)(xlb + ((t*8+gg)<<7) + sl);
        acA[j] = __builtin_amdgcn_mfma_f32_16x16x32_bf16(a0c, bf, acA[j], 0,0,0);
        acB[j] = __builtin_amdgcn_mfma_f32_16x16x32_bf16(a1c, bf, acB[j], 0,0,0);
      }
      __builtin_amdgcn_s_setprio(0);
      if(s<5){ a0c=a0n; a1c=a1n; }
    }
    #pragma unroll
    for(int j=0;j<5;j++) GATE_STORE(acA[j], acB[j], 2*j)
  }
  // ---- group kappa=5 (10 K-steps, 4 col-tiles) ----
  {
    f32x4 acA[4], acB[4];
    #pragma unroll
    for(int j=0;j<4;j++)
      #pragma unroll
      for(int r=0;r<4;r++){ acA[j][r]=g5b[ca+r]; acB[j][r]=g5b[64+ca+r]; }
    const unsigned short* ap0=&Apack[(48 + (w  )*10)*512 + lane*8];
    const unsigned short* ap1=&Apack[(48 + (w+4)*10)*512 + lane*8];
    bf16x8 a0c=*(const bf16x8*)&ap0[0];
    bf16x8 a1c=*(const bf16x8*)&ap1[0];
    #pragma unroll
    for(int s=0;s<10;s++){
      bf16x8 a0n, a1n;
      if(s<9){ a0n=*(const bf16x8*)&ap0[(s+1)*512]; a1n=*(const bf16x8*)&ap1[(s+1)*512]; }
      int dt=s>>1;
      int sl = ((((s&1)*32 + halfk*8)*2) ^ (gg<<4));
      __builtin_amdgcn_s_setprio(1);
      #pragma unroll
      for(int j=0;j<4;j++){
        int t=2*j+tau2+dt;
        bf16x8 bf = *(const bf16x8*)(xlb + ((t*8+gg)<<7) + sl);
        acA[j] = __builtin_amdgcn_mfma_f32_16x16x32_bf16(a0c, bf, acA[j], 0,0,0);
        acB[j] = __builtin_amdgcn_mfma_f32_16x16x32_bf16(a1c, bf, acB[j], 0,0,0);
      }
      __builtin_amdgcn_s_setprio(0);
      if(s<9){ a0c=a0n; a1c=a1n; }
    }
    #pragma unroll
    for(int j=0;j<4;j++) GATE_STORE(acA[j], acB[j], 10+2*j)
  }
  // ---- group kappa=7 (14 K-steps, 3 col-tiles) ----
  {
    f32x4 acA[3], acB[3];
    #pragma unroll
    for(int j=0;j<3;j++)
      #pragma unroll
      for(int r=0;r<4;r++){ acA[j][r]=g7b[ca+r]; acB[j][r]=g7b[64+ca+r]; }
    const unsigned short* ap0=&Apack[(128 + (w  )*14)*512 + lane*8];
    const unsigned short* ap1=&Apack[(128 + (w+4)*14)*512 + lane*8];
    bf16x8 a0c=*(const bf16x8*)&ap0[0];
    bf16x8 a1c=*(const bf16x8*)&ap1[0];
    #pragma unroll
    for(int s=0;s<14;s++){
      bf16x8 a0n, a1n;
      if(s<13){ a0n=*(const bf16x8*)&ap0[(s+1)*512]; a1n=*(const bf16x8*)&ap1[(s+1)*512]; }
      int dt=s>>1;
      int sl = ((((s&1)*32 + halfk*8)*2) ^ (gg<<4));
      __builtin_amdgcn_s_setprio(1);
      #pragma unroll
      for(int j=0;j<3;j++){
        int t=2*j+tau2+dt;
        bf16x8 bf = *(const bf16x8*)(xlb + ((t*8+gg)<<7) + sl);
        acA[j] = __builtin_amdgcn_mfma_f32_16x16x32_bf16(a0c, bf, acA[j], 0,0,0);
        acB[j] = __builtin_amdgcn_mfma_f32_16x16x32_bf16(a1c, bf, acB[j], 0,0,0);
      }
      __builtin_amdgcn_s_setprio(0);
      if(s<13){ a0c=a0n; a1c=a1n; }
    }
    #pragma unroll
    for(int j=0;j<3;j++) GATE_STORE(acA[j], acB[j], 18+2*j)
  }
  #undef GATE_STORE

  // ---- fc via MFMA ----
  const int tcol = lane&15, hq = lane>>4;
  const int hm = (hq==3)? 0 : hq;
  bf16x8 b2 = *(const bf16x8*)&fcwB[lane*8];
  float fcbv = (tcol<12)? fcb[tcol] : 0.f;
  f32x4 d2[8];
  #pragma unroll
  for(int g=0; g<8; g++){
    bf16x8 a2 = *(const bf16x8*)&Glw[tcol*192 + ((g ^ (tcol&7))*24) + hm*8];
    f32x4 ini = {fcbv, fcbv, fcbv, fcbv};
    d2[g] = __builtin_amdgcn_mfma_f32_16x16x32_bf16(a2, b2, ini, 0,0,0);
  }
  __syncthreads();

  if(tcol<12){
    float rwa[4], rba[4];
    #pragma unroll
    for(int r=0;r<4;r++){ int c=w*16+hq*4+r; rwa[r]=rw[c]; rba[r]=rb[c]; }
    #pragma unroll
    for(int g=0; g<8; g++){
      float xv=xres[g][tcol];
      #pragma unroll
      for(int r=0;r<4;r++){
        int c=w*16+hq*4+r;
        float tv = fmaxf(d2[g][r], 0.f);
        float xr = xv*rwa[r]+rba[r];
        U.XP[g][c*12+tcol] = fmaxf(xr+tv, 0.f);
      }
    }
  }
  __syncthreads();

  if(tid<192){
    int p=tid>>1, h=tid&1;
    int g=p/12, t=p-(p/12)*12;
    float s=0.f;
    for(int c=h*32;c<h*32+32;c++) s+=U.XP[g][c*12+t];
    s += __shfl_xor(s,1,64);
    float mu=s*(1.f/64.f);
    float q=0.f;
    for(int c=h*32;c<h*32+32;c++){float d=U.XP[g][c*12+t]-mu;q+=d*d;}
    q += __shfl_xor(q,1,64);
    if(h==0){ mu8[g][t]=mu; rs8[g][t]=rsqrtf(q*(1.f/64.f)+EPS); }
  }
  __syncthreads();
  for(int o=tid;o<1536;o+=256){
    int g=o/192; int q4=o-g*192;
    int c=q4/3; int tb=(q4-c*3)*4;
    float4 vv = *(const float4*)&U.XP[g][c*12+tb];
    float gl=gln[c], bl=bln[c];
    float4 ov;
    ov.x=(vv.x-mu8[g][tb+0])*rs8[g][tb+0]*gl+bl;
    ov.y=(vv.y-mu8[g][tb+1])*rs8[g][tb+1]*gl+bl;
    ov.z=(vv.z-mu8[g][tb+2])*rs8[g][tb+2]*gl+bl;
    ov.w=(vv.w-mu8[g][tb+3])*rs8[g][tb+3]*gl+bl;
    *(float4*)&out[(long)(bn0+g)*768 + c*12 + tb] = ov;
  }
}

// ---------------- launch ----------------
extern "C" void kernel_launch(void* const* d_in, const int* in_sizes, int n_in,
                              void* d_out, int out_size, void* d_ws, size_t ws_size,
                              hipStream_t stream){
  const float* x    =(const float*)d_in[0];
  const float* res  =(const float*)d_in[1];
  const float* posT =(const float*)d_in[2];
  const float* gT   =(const float*)d_in[3];
  const float* bT   =(const float*)d_in[4];
  const float* wq   =(const float*)d_in[5];
  const float* wk   =(const float*)d_in[6];
  const float* wv   =(const float*)d_in[7];
  const float* fcW  =(const float*)d_in[8];
  const float* prw  =(const float*)d_in[9];
  const float* prb  =(const float*)d_in[10];
  const float* posS =(const float*)d_in[11];
  const float* gS   =(const float*)d_in[12];
  const float* bS   =(const float*)d_in[13];
  const float* swq  =(const float*)d_in[14];
  const float* swk  =(const float*)d_in[15];
  const float* cheb =(const float*)d_in[16];
  const float* adj  =(const float*)d_in[17];
  const float* cmask=(const float*)d_in[18];
  const float* theta=(const float*)d_in[19];
  const float* g3w=(const float*)d_in[20]; const float* g3b=(const float*)d_in[21];
  const float* g5w=(const float*)d_in[22]; const float* g5b=(const float*)d_in[23];
  const float* g7w=(const float*)d_in[24]; const float* g7b=(const float*)d_in[25];
  const float* fcw=(const float*)d_in[26]; const float* fcb=(const float*)d_in[27];
  const float* rw =(const float*)d_in[28]; const float* rb =(const float*)d_in[29];
  const float* gln=(const float*)d_in[30]; const float* bln=(const float*)d_in[31];

  float* outp=(float*)d_out;
  float* scores = outp + 12582912;

  float* wsf=(float*)d_ws;
  float* TEmx = wsf;                          // 196608 f
  float* qkv  = TEmx + 196608;                // 55296 f
  float* TATpre = qkv + 55296;                // 196608 f
  unsigned short* SEb = (unsigned short*)(TATpre + 196608);      // (unused, kept for layout)
  unsigned short* SQb = (unsigned short*)((float*)SEb + 4194304); // 786432 f
  unsigned short* SKb = (unsigned short*)((float*)SQb + 786432);  // 786432 f
  unsigned* mcT = (unsigned*)((float*)SKb + 786432);              // 3145728 f
  float* rhsT  = (float*)mcT + 3145728;                           // 589824 f
  unsigned short* Apack = (unsigned short*)(rhsT + 589824);       // 122880 u16
  unsigned short* Wpack = Apack + 122880;                         // 98304 u16
  unsigned short* Wpack2 = Wpack + 98304;                         // 294912 u16
  unsigned short* TEb = Wpack2 + 294912;                          // 196608 u16
  unsigned short* fcwB = TEb + 196608;                            // 512 u16
  unsigned short* ctxb = fcwB + 512;                              // 18432 u16
  unsigned short* fcWB2 = ctxb + 18432;                           // 98304 u16
  float* muT = (float*)(fcWB2 + 98304);                           // 192 f
  float* rsT = muT + 192;                                         // 192 f

  kbp1_prep<<<dim3(493),dim3(256),0,stream>>>(g3w,g5w,g7w,swq,swk,wq,wk,wv,fcw,fcW,
                                              Apack,Wpack,Wpack2,fcwB,fcWB2,
                                              x,posT,gT,bT,TEmx,TEb);
  k2_qkv<<<dim3(984),dim3(256),0,stream>>>(TEb,Wpack2,qkv,adj,cmask,cheb,mcT);
  k3_attn<<<dim3(48),dim3(256),0,stream>>>(qkv,res,scores,ctxb);
  k4a_mm<<<dim3(192),dim3(256),0,stream>>>(ctxb,fcWB2,TEmx,TATpre);
  k4b_stats<<<dim3(192),dim3(256),0,stream>>>(TATpre,muT,rsT);
  k56_semx_sqk<<<dim3(1024),dim3(256),0,stream>>>(TATpre,muT,rsT,prw,prb,posS,gS,bS,
                                                  Wpack,SQb,SKb);
  k7_spatial<<<dim3(768),dim3(256),0,stream>>>(SQb,SKb,mcT,x,rhsT);
  k9_final<<<dim3(2048),dim3(256),0,stream>>>(rhsT,theta,Apack,fcwB,g3b,g5b,g7b,
                                              fcb,rw,rb,gln,bln,x,outp);
}